// Round 14
// baseline (998.346 us; speedup 1.0000x reference)
//
#include <hip/hip_runtime.h>
#include <math.h>

#define CC 256
#define KF 129
#define NBK 8
#define BSZ 32
#define LAT 1024

typedef __attribute__((ext_vector_type(8))) __bf16 bf16x8;
typedef __attribute__((ext_vector_type(4))) float f32x4;
typedef __attribute__((ext_vector_type(4))) unsigned u32x4;

__device__ __forceinline__ float wred(float v){
#pragma unroll
  for (int o = 32; o; o >>= 1) v += __shfl_xor(v, o, 64);
  return v;
}

// f32 -> bf16 bits, round-to-nearest-even
__device__ __forceinline__ unsigned short f2b(float f){
  unsigned u = __builtin_bit_cast(unsigned, f);
  unsigned r = u + 0x7fffu + ((u >> 16) & 1u);
  return (unsigned short)(r >> 16);
}
__device__ __forceinline__ float b2f(unsigned short h){
  unsigned u = ((unsigned)h) << 16;
  return __builtin_bit_cast(float, u);
}

__device__ __forceinline__ bf16x8 ldfrag(const unsigned short* p){
  return __builtin_bit_cast(bf16x8, *(const uint4*)p);
}
__device__ __forceinline__ bf16x8 negf(bf16x8 v){
  u32x4 u = __builtin_bit_cast(u32x4, v);
  u = u ^ 0x80008000u;
  return __builtin_bit_cast(bf16x8, u);
}

// tanh-form GELU
__device__ __forceinline__ float gelu_t(float v){
  float s = v * v;
  float t = v * fmaf(s, -0.0713575f, -1.5957691f);   // -z
  float e = __expf(t);                                // e^{-z}
  return v * __builtin_amdgcn_rcpf(1.0f + e);
}

// ---- staging split for double-buffer: load 8 u16 (one c, 8 k's) / pack+write ----
// LDS layout transposed [c][k], chunk swizzle: (c,k) at c*32 + 8*((k>>3)^((c>>1)&3)) + (k&7)
__device__ __forceinline__ void stage_ld(const unsigned short* __restrict__ gp,
    unsigned short* v, int sc, int w8){
#pragma unroll
  for (int j = 0; j < 8; ++j) v[j] = gp[(size_t)(w8 + j) * CC + sc];
}
__device__ __forceinline__ void stage_wr(const unsigned short* v,
    unsigned short* lds, int sc, int w8){
  uint4 u;
  u.x = (unsigned)v[0] | ((unsigned)v[1] << 16);
  u.y = (unsigned)v[2] | ((unsigned)v[3] << 16);
  u.z = (unsigned)v[4] | ((unsigned)v[5] << 16);
  u.w = (unsigned)v[6] | ((unsigned)v[7] << 16);
  *(uint4*)(lds + sc * 32 + 8 * ((w8 >> 3) ^ ((sc >> 1) & 3))) = u;
}

// B-fragment: lane (g,lr) reads B^T[c = nf*16+lr][k = g*8 .. g*8+7]
__device__ __forceinline__ bf16x8 bfrag(const unsigned short* lds, int g, int lr, int nf){
  int c = nf * 16 + lr;
  return ldfrag(lds + c * 32 + 8 * (g ^ ((c >> 1) & 3)));
}

// ---- init ----
__global__ __launch_bounds__(256) void k_init(const float* __restrict__ mw1,
    const float* __restrict__ mw2,
    unsigned short* __restrict__ Awr, unsigned short* __restrict__ Awi,
    unsigned short* __restrict__ Ahc, unsigned short* __restrict__ Ahs,
    unsigned short* __restrict__ Air, unsigned short* __restrict__ Aii,
    unsigned short* __restrict__ w1s, unsigned short* __restrict__ w2c){
  int i = blockIdx.x * 256 + threadIdx.x;            // < 262144
  if (i < 49152) {                                   // Aw: 192 x 256 (kw padded)
    int m = i >> 8, w = i & 255;
    float t = (float)((m * w) & 255) / 128.0f;
    Awr[i] = f2b(cospif(t) * 0.0625f);
    Awi[i] = f2b(-sinpif(t) * 0.0625f);
  }
  if (i < 65536) {                                   // Ah: 256 x 256
    int k = i >> 8, h = i & 255;
    float t = (float)((k * h) & 255) / 128.0f;
    Ahc[i] = f2b(cospif(t) * 0.0625f);
    Ahs[i] = f2b(sinpif(t) * 0.0625f);
  }
  if (i < 32768) {                                   // Awinv: 256(w) x 128(kw), c_k folded
    int w = i >> 7, kw = i & 127;
    float t = (float)((kw * w) & 255) / 128.0f;
    float c = (kw == 0) ? 0.0625f : 0.125f;
    Air[i] = f2b(cospif(t) * c);
    Aii[i] = f2b(-sinpif(t) * c);
  }
  {
    int l = i >> 8, k2 = i & 255;
    w1s[(l << 8) | (k2 ^ ((l & 7) << 3))] = f2b(mw1[k2 * LAT + l]);
    int n = i >> 10, l2 = i & 1023;
    int ch = l2 >> 6, kk = l2 & 63;
    w2c[(size_t)((ch << 8) + n) * 64 + (kk ^ ((n & 7) << 3))] = f2b(mw2[l2 * CC + n]);
  }
}

// ---- LN1: bf16 out only ----
__global__ __launch_bounds__(256) void k_ln1(const float* __restrict__ in,
    const float* __restrict__ g, const float* __restrict__ b,
    unsigned short* __restrict__ outb){
  int lane = threadIdx.x & 63;
  size_t row = (size_t)blockIdx.x * 4 + (threadIdx.x >> 6);
  float4 v = ((const float4*)(in + row * CC))[lane];
  float s = wred(v.x + v.y + v.z + v.w);
  float q = wred(v.x*v.x + v.y*v.y + v.z*v.z + v.w*v.w);
  float mean = s * (1.0f/CC);
  float rstd = rsqrtf(q * (1.0f/CC) - mean*mean + 1e-5f);
  float4 gv = ((const float4*)g)[lane];
  float4 bv = ((const float4*)b)[lane];
  ushort4 ob;
  ob.x = f2b((v.x - mean) * rstd * gv.x + bv.x);
  ob.y = f2b((v.y - mean) * rstd * gv.y + bv.y);
  ob.z = f2b((v.z - mean) * rstd * gv.z + bv.z);
  ob.w = f2b((v.w - mean) * rstd * gv.w + bv.w);
  ((ushort4*)(outb + row * CC))[lane] = ob;
}

// ---- LN2: bf16 in, bf16 out ----
__global__ __launch_bounds__(256) void k_ln2(const unsigned short* __restrict__ in,
    const float* __restrict__ g, const float* __restrict__ b,
    unsigned short* __restrict__ out){
  int lane = threadIdx.x & 63;
  size_t row = (size_t)blockIdx.x * 4 + (threadIdx.x >> 6);
  ushort4 uv = ((const ushort4*)(in + row * CC))[lane];
  float4 v;
  v.x = b2f(uv.x); v.y = b2f(uv.y); v.z = b2f(uv.z); v.w = b2f(uv.w);
  float s = wred(v.x + v.y + v.z + v.w);
  float q = wred(v.x*v.x + v.y*v.y + v.z*v.z + v.w*v.w);
  float mean = s * (1.0f/CC);
  float rstd = rsqrtf(q * (1.0f/CC) - mean*mean + 1e-5f);
  float4 gv = ((const float4*)g)[lane];
  float4 bv = ((const float4*)b)[lane];
  ushort4 o;
  o.x = f2b((v.x - mean) * rstd * gv.x + bv.x);
  o.y = f2b((v.y - mean) * rstd * gv.y + bv.y);
  o.z = f2b((v.z - mean) * rstd * gv.z + bv.z);
  o.w = f2b((v.w - mean) * rstd * gv.w + bv.w);
  ((ushort4*)(out + row * CC))[lane] = o;
}

// ---- W-forward rDFT as MFMA GEMM, double-buffered staging (1 barrier/ks) ----
__global__ __launch_bounds__(256) void k_gw(const unsigned short* __restrict__ h1b,
    const unsigned short* __restrict__ Awr, const unsigned short* __restrict__ Awi,
    unsigned short* __restrict__ Xr, unsigned short* __restrict__ Xi){
  __shared__ __align__(16) unsigned short sb[2][2048];
  int tid = threadIdx.x, wv = tid >> 6, lane = tid & 63, g = lane >> 4, lr = lane & 15;
  int sc = tid & 63, w8 = (tid >> 6) * 8;
  int bh = blockIdx.x, m0 = blockIdx.y * 64, n0 = blockIdx.z * 64;
  const unsigned short* Bsrc = h1b + (size_t)bh * 65536 + n0;
  int arow = m0 + wv * 16 + lr;
  f32x4 aR[4], aI[4];
#pragma unroll
  for (int i = 0; i < 4; ++i) { aR[i] = (f32x4){0,0,0,0}; aI[i] = (f32x4){0,0,0,0}; }
  unsigned short vb[8];
  stage_ld(Bsrc, vb, sc, w8);
  stage_wr(vb, sb[0], sc, w8);
  __syncthreads();
  for (int ks = 0; ks < 8; ++ks) {
    int cur = ks & 1;
    if (ks < 7) stage_ld(Bsrc + (size_t)(ks + 1) * 32 * CC, vb, sc, w8);
    bf16x8 ar = ldfrag(Awr + (size_t)arow * 256 + ks * 32 + g * 8);
    bf16x8 ai = ldfrag(Awi + (size_t)arow * 256 + ks * 32 + g * 8);
#pragma unroll
    for (int nf = 0; nf < 4; ++nf) {
      bf16x8 bf = bfrag(sb[cur], g, lr, nf);
      aR[nf] = __builtin_amdgcn_mfma_f32_16x16x32_bf16(ar, bf, aR[nf], 0, 0, 0);
      aI[nf] = __builtin_amdgcn_mfma_f32_16x16x32_bf16(ai, bf, aI[nf], 0, 0, 0);
    }
    if (ks < 7) {
      stage_wr(vb, sb[cur ^ 1], sc, w8);
      __syncthreads();
    }
  }
  int b = bh >> 8, h = bh & 255;
#pragma unroll
  for (int nf = 0; nf < 4; ++nf) {
    int c = n0 + nf * 16 + lr;
#pragma unroll
    for (int r = 0; r < 4; ++r) {
      int kw = m0 + wv * 16 + g * 4 + r;
      if (kw < KF) {
        size_t o = ((size_t)(b * KF + kw) * 256 + h) * 256 + c;
        Xr[o] = f2b(aR[nf][r]);
        Xi[o] = f2b(aI[nf][r]);
      }
    }
  }
}

// ---- H-direction complex DFT, M-merged x2, double-buffered staging ----
template<int INV>
__global__ __launch_bounds__(256) void k_gh(const unsigned short* __restrict__ Bre,
    const unsigned short* __restrict__ Bim, const unsigned short* __restrict__ Ac,
    const unsigned short* __restrict__ As, unsigned short* __restrict__ Ore,
    unsigned short* __restrict__ Oim){
  __shared__ __align__(16) unsigned short sr[2][2048], si[2][2048];
  int tid = threadIdx.x, wv = tid >> 6, lane = tid & 63, g = lane >> 4, lr = lane & 15;
  int sc = tid & 63, w8 = (tid >> 6) * 8;
  int bkw = blockIdx.x, m0 = blockIdx.y * 128, n0 = blockIdx.z * 64;
  const unsigned short* srcR = Bre + (size_t)bkw * 65536 + n0;
  const unsigned short* srcI = Bim + (size_t)bkw * 65536 + n0;
  f32x4 accR[2][4], accI[2][4];
#pragma unroll
  for (int m = 0; m < 2; ++m)
#pragma unroll
    for (int i = 0; i < 4; ++i) { accR[m][i] = (f32x4){0,0,0,0}; accI[m][i] = (f32x4){0,0,0,0}; }
  unsigned short vr[8], vi[8];
  stage_ld(srcR, vr, sc, w8);
  stage_ld(srcI, vi, sc, w8);
  stage_wr(vr, sr[0], sc, w8);
  stage_wr(vi, si[0], sc, w8);
  __syncthreads();
  for (int ks = 0; ks < 8; ++ks) {
    int cur = ks & 1;
    if (ks < 7) {
      stage_ld(srcR + (size_t)(ks + 1) * 32 * CC, vr, sc, w8);
      stage_ld(srcI + (size_t)(ks + 1) * 32 * CC, vi, sc, w8);
    }
    bf16x8 bR[4], bI[4];
#pragma unroll
    for (int nf = 0; nf < 4; ++nf) { bR[nf] = bfrag(sr[cur], g, lr, nf); bI[nf] = bfrag(si[cur], g, lr, nf); }
#pragma unroll
    for (int mt = 0; mt < 2; ++mt) {
      int arow = m0 + mt * 64 + wv * 16 + lr;
      bf16x8 ac = ldfrag(Ac + (size_t)arow * 256 + ks * 32 + g * 8);
      bf16x8 as = ldfrag(As + (size_t)arow * 256 + ks * 32 + g * 8);
      bf16x8 asn = negf(as);
#pragma unroll
      for (int nf = 0; nf < 4; ++nf) {
        accR[mt][nf] = __builtin_amdgcn_mfma_f32_16x16x32_bf16(ac, bR[nf], accR[mt][nf], 0, 0, 0);
        accR[mt][nf] = __builtin_amdgcn_mfma_f32_16x16x32_bf16(INV ? asn : as, bI[nf], accR[mt][nf], 0, 0, 0);
        accI[mt][nf] = __builtin_amdgcn_mfma_f32_16x16x32_bf16(ac, bI[nf], accI[mt][nf], 0, 0, 0);
        accI[mt][nf] = __builtin_amdgcn_mfma_f32_16x16x32_bf16(INV ? as : asn, bR[nf], accI[mt][nf], 0, 0, 0);
      }
    }
    if (ks < 7) {
      stage_wr(vr, sr[cur ^ 1], sc, w8);
      stage_wr(vi, si[cur ^ 1], sc, w8);
      __syncthreads();
    }
  }
  if (!INV) {
#pragma unroll
    for (int mt = 0; mt < 2; ++mt)
#pragma unroll
      for (int nf = 0; nf < 4; ++nf) {
        int c = n0 + nf * 16 + lr;
#pragma unroll
        for (int r = 0; r < 4; ++r) {
          int kh = m0 + mt * 64 + wv * 16 + g * 4 + r;
          size_t o = ((size_t)bkw * 256 + kh) * 256 + c;
          Ore[o] = f2b(accR[mt][nf][r]);
          Oim[o] = f2b(accI[mt][nf][r]);
        }
      }
  } else {
    int b = (bkw >= KF) ? 1 : 0;
    int kw = bkw - b * KF;
#pragma unroll
    for (int mt = 0; mt < 2; ++mt)
#pragma unroll
      for (int nf = 0; nf < 4; ++nf) {
        int c = n0 + nf * 16 + lr;
#pragma unroll
        for (int r = 0; r < 4; ++r) {
          int h = m0 + mt * 64 + wv * 16 + g * 4 + r;
          size_t o = (((size_t)b * 256 + h) * KF + kw) * 256 + c;
          Ore[o] = f2b(accR[mt][nf][r]);
          Oim[o] = f2b(accI[mt][nf][r]);
        }
      }
  }
}

// ---- W-inverse rDFT + Nyquist + residuals, M-merged x2; out1 stored bf16 ----
__global__ __launch_bounds__(256) void k_gwi(const unsigned short* __restrict__ Zr,
    const unsigned short* __restrict__ Zi, const unsigned short* __restrict__ Ar,
    const unsigned short* __restrict__ Ai, const float* __restrict__ x,
    const unsigned short* __restrict__ h1b, unsigned short* __restrict__ out1b){
  __shared__ __align__(16) unsigned short sr[2][2048], si[2][2048];
  int tid = threadIdx.x, wv = tid >> 6, lane = tid & 63, g = lane >> 4, lr = lane & 15;
  int sc = tid & 63, w8 = (tid >> 6) * 8;
  int bh = blockIdx.x, m0 = blockIdx.y * 128, n0 = blockIdx.z * 64;
  const unsigned short* srcR = Zr + (size_t)bh * 33024 + n0;
  const unsigned short* srcI = Zi + (size_t)bh * 33024 + n0;
  f32x4 acc[2][4];
#pragma unroll
  for (int m = 0; m < 2; ++m)
#pragma unroll
    for (int i = 0; i < 4; ++i) acc[m][i] = (f32x4){0,0,0,0};
  unsigned short vr[8], vi[8];
  stage_ld(srcR, vr, sc, w8);
  stage_ld(srcI, vi, sc, w8);
  stage_wr(vr, sr[0], sc, w8);
  stage_wr(vi, si[0], sc, w8);
  __syncthreads();
  for (int ks = 0; ks < 4; ++ks) {
    int cur = ks & 1;
    if (ks < 3) {
      stage_ld(srcR + (size_t)(ks + 1) * 32 * CC, vr, sc, w8);
      stage_ld(srcI + (size_t)(ks + 1) * 32 * CC, vi, sc, w8);
    }
    bf16x8 bR[4], bI[4];
#pragma unroll
    for (int nf = 0; nf < 4; ++nf) { bR[nf] = bfrag(sr[cur], g, lr, nf); bI[nf] = bfrag(si[cur], g, lr, nf); }
#pragma unroll
    for (int mt = 0; mt < 2; ++mt) {
      int arow = m0 + mt * 64 + wv * 16 + lr;
      bf16x8 ar = ldfrag(Ar + (size_t)arow * 128 + ks * 32 + g * 8);
      bf16x8 ai = ldfrag(Ai + (size_t)arow * 128 + ks * 32 + g * 8);
#pragma unroll
      for (int nf = 0; nf < 4; ++nf) {
        acc[mt][nf] = __builtin_amdgcn_mfma_f32_16x16x32_bf16(ar, bR[nf], acc[mt][nf], 0, 0, 0);
        acc[mt][nf] = __builtin_amdgcn_mfma_f32_16x16x32_bf16(ai, bI[nf], acc[mt][nf], 0, 0, 0);
      }
    }
    if (ks < 3) {
      stage_wr(vr, sr[cur ^ 1], sc, w8);
      stage_wr(vi, si[cur ^ 1], sc, w8);
      __syncthreads();
    }
  }
#pragma unroll
  for (int nf = 0; nf < 4; ++nf) {
    int c = n0 + nf * 16 + lr;
    float zn = b2f(Zr[(size_t)bh * 33024 + 32768 + c]) * 0.0625f;  // kw=128, sin=0
#pragma unroll
    for (int mt = 0; mt < 2; ++mt)
#pragma unroll
      for (int r = 0; r < 4; ++r) {
        int w = m0 + mt * 64 + wv * 16 + g * 4 + r;
        size_t idx = ((size_t)bh * 256 + w) * 256 + c;
        float ny = (w & 1) ? -zn : zn;
        out1b[idx] = f2b(acc[mt][nf][r] + ny + b2f(h1b[idx]) + x[idx]);
      }
  }
}

// ---- block-diagonal complex MLP: 16 positions/block, weights reg-cached ----
__global__ __launch_bounds__(256) void k_bmlp(const unsigned short* __restrict__ Yr,
    const unsigned short* __restrict__ Yi, const float* __restrict__ w1,
    const float* __restrict__ b1, const float* __restrict__ w2,
    const float* __restrict__ b2, unsigned short* __restrict__ Or,
    unsigned short* __restrict__ Oi){
  __shared__ unsigned short sx[2][16][256];   // r/i, pos, chan (16 KB)
  __shared__ unsigned short s1[2][16][256];   // relu(o1) bf16  (16 KB)
  int tid = threadIdx.x;
  int n = tid >> 5, o = tid & 31;
  size_t pos0 = (size_t)blockIdx.x * 16;
  {
    int p = tid >> 4, cb = (tid & 15) * 16;
#pragma unroll
    for (int q = 0; q < 2; ++q) {
      *(uint4*)&sx[0][p][cb + q * 8] = *(const uint4*)(Yr + (pos0 + p) * CC + cb + q * 8);
      *(uint4*)&sx[1][p][cb + q * 8] = *(const uint4*)(Yi + (pos0 + p) * CC + cb + q * 8);
    }
  }
  // register-cache this thread's weight columns (f32, exact)
  float w1r[32], w1i[32], w2r[32], w2i[32];
#pragma unroll
  for (int i = 0; i < 32; ++i) {
    w1r[i] = w1[(n * BSZ + i) * BSZ + o];
    w1i[i] = w1[NBK * BSZ * BSZ + (n * BSZ + i) * BSZ + o];
    w2r[i] = w2[(n * BSZ + i) * BSZ + o];
    w2i[i] = w2[NBK * BSZ * BSZ + (n * BSZ + i) * BSZ + o];
  }
  float br = b1[n * BSZ + o], bi = b1[NBK * BSZ + n * BSZ + o];
  float cr = b2[n * BSZ + o], ci = b2[NBK * BSZ + n * BSZ + o];
  __syncthreads();
  for (int pt = 0; pt < 4; ++pt) {
    float a1r[4], a1i[4];
#pragma unroll
    for (int p = 0; p < 4; ++p) { a1r[p] = br; a1i[p] = bi; }
#pragma unroll
    for (int i = 0; i < 32; ++i) {
#pragma unroll
      for (int p = 0; p < 4; ++p) {
        float xr = b2f(sx[0][pt * 4 + p][n * BSZ + i]);
        float xi = b2f(sx[1][pt * 4 + p][n * BSZ + i]);
        a1r[p] += xr * w1r[i] - xi * w1i[i];
        a1i[p] += xi * w1r[i] + xr * w1i[i];
      }
    }
#pragma unroll
    for (int p = 0; p < 4; ++p) {
      s1[0][pt * 4 + p][n * BSZ + o] = f2b(fmaxf(a1r[p], 0.f));
      s1[1][pt * 4 + p][n * BSZ + o] = f2b(fmaxf(a1i[p], 0.f));
    }
  }
  __syncthreads();
  for (int pt = 0; pt < 4; ++pt) {
    float a2r[4], a2i[4];
#pragma unroll
    for (int p = 0; p < 4; ++p) { a2r[p] = cr; a2i[p] = ci; }
#pragma unroll
    for (int i = 0; i < 32; ++i) {
#pragma unroll
      for (int p = 0; p < 4; ++p) {
        float xr = b2f(s1[0][pt * 4 + p][n * BSZ + i]);
        float xi = b2f(s1[1][pt * 4 + p][n * BSZ + i]);
        a2r[p] += xr * w2r[i] - xi * w2i[i];
        a2i[p] += xi * w2r[i] + xr * w2i[i];
      }
    }
#pragma unroll
    for (int p = 0; p < 4; ++p) {
      float vr = a2r[p], vi = a2i[p];
      size_t idx = (pos0 + pt * 4 + p) * CC + n * BSZ + o;
      Or[idx] = f2b((fabsf(vr) > 0.01f) ? (vr - copysignf(0.01f, vr)) : 0.f);
      Oi[idx] = f2b((fabsf(vi) > 0.01f) ? (vi - copysignf(0.01f, vi)) : 0.f);
    }
  }
}

// ---- fused MLP: round-10 structure (stage-2 N-split, sw2 staged) + w1 reg-prefetch ----
__global__ __launch_bounds__(256, 2) void k_mlp(const unsigned short* __restrict__ h2,
    const unsigned short* __restrict__ w1s, const float* __restrict__ mb1,
    const unsigned short* __restrict__ w2c, const float* __restrict__ mb2,
    const unsigned short* __restrict__ residb, float* __restrict__ out){
  __shared__ __align__(16) unsigned short sw1[64 * 256];   // [l_local][k ^ ((l&7)<<3)]
  __shared__ __align__(16) unsigned short sw2[256 * 64];   // [n][kk ^ ((n&7)<<3)]
  __shared__ __align__(16) unsigned short mids[64][64];    // [row][e ^ ((row&7)<<3)]
  int tid = threadIdx.x;
  int wave = tid >> 6, lane = tid & 63;
  int g = lane >> 4, lr = lane & 15;
  size_t row0 = (size_t)blockIdx.x * 64;
  bf16x8 areg[8];
#pragma unroll
  for (int ks = 0; ks < 8; ++ks)
    areg[ks] = ldfrag(h2 + (row0 + wave * 16 + lr) * CC + ks * 32 + g * 8);
  const uint4* s1g = (const uint4*)w1s;
  const uint4* s2g = (const uint4*)w2c;
  uint4* d1 = (uint4*)sw1;
  uint4* d2 = (uint4*)sw2;
  uint4 r1[8];
#pragma unroll
  for (int it = 0; it < 8; ++it) r1[it] = s1g[it * 256 + tid];   // prefetch ch=0 w1
  f32x4 acc2[4][4];      // [m-frag][n-frag]; wave owns cols [wave*64, wave*64+64)
#pragma unroll
  for (int mi = 0; mi < 4; ++mi)
#pragma unroll
    for (int ni = 0; ni < 4; ++ni) acc2[mi][ni] = (f32x4){0.f, 0.f, 0.f, 0.f};
  for (int ch = 0; ch < 16; ++ch) {
    __syncthreads();
    {
      // issue sw2 global loads first so their latency overlaps the sw1 LDS writes
      uint4 t2[8];
#pragma unroll
      for (int it = 0; it < 8; ++it) t2[it] = s2g[(size_t)ch * 2048 + it * 256 + tid];
#pragma unroll
      for (int it = 0; it < 8; ++it) d1[it * 256 + tid] = r1[it];
#pragma unroll
      for (int it = 0; it < 8; ++it) d2[it * 256 + tid] = t2[it];
    }
    __syncthreads();
    if (ch < 15) {
#pragma unroll
      for (int it = 0; it < 8; ++it)
        r1[it] = s1g[(size_t)(ch + 1) * 2048 + it * 256 + tid];  // prefetch next w1
    }
    // stage 1: wave computes its 16 rows x 64 latent (4 indep chains)
    f32x4 acc1[4];
#pragma unroll
    for (int s = 0; s < 4; ++s) acc1[s] = (f32x4){0.f, 0.f, 0.f, 0.f};
#pragma unroll
    for (int ks = 0; ks < 8; ++ks) {
#pragma unroll
      for (int s = 0; s < 4; ++s) {
        int l = s * 16 + lr;
        bf16x8 bf = ldfrag(sw1 + l * 256 + ((ks * 32 + g * 8) ^ ((lr & 7) << 3)));
        acc1[s] = __builtin_amdgcn_mfma_f32_16x16x32_bf16(areg[ks], bf, acc1[s], 0, 0, 0);
      }
    }
    int l0 = ch * 64;
#pragma unroll
    for (int s = 0; s < 4; ++s) {
      float bias = mb1[l0 + s * 16 + lr];
#pragma unroll
      for (int r = 0; r < 4; ++r) {
        int row = wave * 16 + g * 4 + r;
        mids[row][(s * 16 + lr) ^ ((row & 7) << 3)] = f2b(gelu_t(acc1[s][r] + bias));
      }
    }
    __syncthreads();   // mids visible to all waves
    // stage 2: wave computes all 64 rows x its 64-col slice
#pragma unroll
    for (int ks = 0; ks < 2; ++ks) {
      bf16x8 af[4], bfv[4];
#pragma unroll
      for (int mi = 0; mi < 4; ++mi)
        af[mi] = ldfrag(&mids[mi * 16 + lr][(ks * 32 + g * 8) ^ ((lr & 7) << 3)]);
#pragma unroll
      for (int ni = 0; ni < 4; ++ni)
        bfv[ni] = ldfrag(sw2 + (wave * 64 + ni * 16 + lr) * 64 + ((ks * 32 + g * 8) ^ ((lr & 7) << 3)));
#pragma unroll
      for (int mi = 0; mi < 4; ++mi)
#pragma unroll
        for (int ni = 0; ni < 4; ++ni)
          acc2[mi][ni] = __builtin_amdgcn_mfma_f32_16x16x32_bf16(af[mi], bfv[ni], acc2[mi][ni], 0, 0, 0);
    }
  }
#pragma unroll
  for (int mi = 0; mi < 4; ++mi)
#pragma unroll
    for (int ni = 0; ni < 4; ++ni) {
      int n = wave * 64 + ni * 16 + lr;
      float bias = mb2[n];
#pragma unroll
      for (int r = 0; r < 4; ++r) {
        size_t idx = (row0 + mi * 16 + g * 4 + r) * CC + n;
        out[idx] = acc2[mi][ni][r] + bias + b2f(residb[idx]);
      }
    }
}

extern "C" void kernel_launch(void* const* d_in, const int* in_sizes, int n_in,
                              void* d_out, int out_size, void* d_ws, size_t ws_size,
                              hipStream_t stream) {
  const float* x   = (const float*)d_in[0];
  const float* n1g = (const float*)d_in[1];
  const float* n1b = (const float*)d_in[2];
  const float* n2g = (const float*)d_in[3];
  const float* n2b = (const float*)d_in[4];
  const float* w1  = (const float*)d_in[5];
  const float* b1  = (const float*)d_in[6];
  const float* w2  = (const float*)d_in[7];
  const float* b2  = (const float*)d_in[8];
  const float* mw1 = (const float*)d_in[9];
  const float* mb1 = (const float*)d_in[10];
  const float* mw2 = (const float*)d_in[11];
  const float* mb2 = (const float*)d_in[12];
  float* out = (float*)d_out;

  char* ws = (char*)d_ws;
  unsigned short* o1b = (unsigned short*)(ws);                // out1 bf16, 67,108,864 B
  unsigned short* h1b = (unsigned short*)(ws + 134217728ull); // 67,108,864 B; later h2b
  unsigned short* Xr  = (unsigned short*)(ws + 201326592ull); // 33,816,576 B (also O_r)
  unsigned short* Xi  = (unsigned short*)(ws + 235143168ull); // 33,816,576 B (also O_i)
  unsigned short* Yr  = (unsigned short*)(ws + 268959744ull); // 33,816,576 B (also Z_r)
  unsigned short* Yi  = (unsigned short*)(ws + 302776320ull); // 33,816,576 B (also Z_i)
  unsigned short* Awr = (unsigned short*)(ws + 336592896ull); // 98,304 B
  unsigned short* Awi = (unsigned short*)(ws + 336691200ull); // 98,304 B
  unsigned short* Ahc = (unsigned short*)(ws + 336789504ull); // 131,072 B
  unsigned short* Ahs = (unsigned short*)(ws + 336920576ull); // 131,072 B
  unsigned short* Air = (unsigned short*)(ws + 337051648ull); // 65,536 B
  unsigned short* Aii = (unsigned short*)(ws + 337117184ull); // 65,536 B
  unsigned short* w1s = (unsigned short*)(ws + 337182720ull); // 524,288 B
  unsigned short* w2c = (unsigned short*)(ws + 337707008ull); // 524,288 B

  k_init<<<1024, 256, 0, stream>>>(mw1, mw2, Awr, Awi, Ahc, Ahs, Air, Aii, w1s, w2c);
  k_ln1<<<32768, 256, 0, stream>>>(x, n1g, n1b, h1b);
  k_gw<<<dim3(512, 3, 4), 256, 0, stream>>>(h1b, Awr, Awi, Xr, Xi);
  k_gh<0><<<dim3(258, 2, 4), 256, 0, stream>>>(Xr, Xi, Ahc, Ahs, Yr, Yi);
  k_bmlp<<<4128, 256, 0, stream>>>(Yr, Yi, w1, b1, w2, b2, Xr, Xi);
  k_gh<1><<<dim3(258, 2, 4), 256, 0, stream>>>(Xr, Xi, Ahc, Ahs, Yr, Yi);
  k_gwi<<<dim3(512, 2, 4), 256, 0, stream>>>(Yr, Yi, Air, Aii, x, h1b, o1b);
  k_ln2<<<32768, 256, 0, stream>>>(o1b, n2g, n2b, h1b);
  k_mlp<<<2048, 256, 0, stream>>>(h1b, w1s, mb1, w2c, mb2, o1b, out);
}

// Round 15
// 811.305 us; speedup vs baseline: 1.2305x; 1.2305x over previous
//
#include <hip/hip_runtime.h>
#include <math.h>

#define CC 256
#define KF 129
#define NBK 8
#define BSZ 32
#define LAT 1024

typedef __attribute__((ext_vector_type(8))) __bf16 bf16x8;
typedef __attribute__((ext_vector_type(4))) float f32x4;
typedef __attribute__((ext_vector_type(4))) unsigned u32x4;

__device__ __forceinline__ float wred(float v){
#pragma unroll
  for (int o = 32; o; o >>= 1) v += __shfl_xor(v, o, 64);
  return v;
}

// f32 -> bf16 bits, round-to-nearest-even
__device__ __forceinline__ unsigned short f2b(float f){
  unsigned u = __builtin_bit_cast(unsigned, f);
  unsigned r = u + 0x7fffu + ((u >> 16) & 1u);
  return (unsigned short)(r >> 16);
}
__device__ __forceinline__ float b2f(unsigned short h){
  unsigned u = ((unsigned)h) << 16;
  return __builtin_bit_cast(float, u);
}

__device__ __forceinline__ bf16x8 ldfrag(const unsigned short* p){
  return __builtin_bit_cast(bf16x8, *(const uint4*)p);
}
__device__ __forceinline__ bf16x8 negf(bf16x8 v){
  u32x4 u = __builtin_bit_cast(u32x4, v);
  u = u ^ 0x80008000u;
  return __builtin_bit_cast(bf16x8, u);
}

// tanh-form GELU
__device__ __forceinline__ float gelu_t(float v){
  float s = v * v;
  float t = v * fmaf(s, -0.0713575f, -1.5957691f);   // -z
  float e = __expf(t);                                // e^{-z}
  return v * __builtin_amdgcn_rcpf(1.0f + e);
}

// ---- staging split for double-buffer: load 8 u16 (one c, 8 k's) / pack+write ----
// LDS layout transposed [c][k], chunk swizzle: (c,k) at c*32 + 8*((k>>3)^((c>>1)&3)) + (k&7)
__device__ __forceinline__ void stage_ld(const unsigned short* __restrict__ gp,
    unsigned short* v, int sc, int w8){
#pragma unroll
  for (int j = 0; j < 8; ++j) v[j] = gp[(size_t)(w8 + j) * CC + sc];
}
__device__ __forceinline__ void stage_wr(const unsigned short* v,
    unsigned short* lds, int sc, int w8){
  uint4 u;
  u.x = (unsigned)v[0] | ((unsigned)v[1] << 16);
  u.y = (unsigned)v[2] | ((unsigned)v[3] << 16);
  u.z = (unsigned)v[4] | ((unsigned)v[5] << 16);
  u.w = (unsigned)v[6] | ((unsigned)v[7] << 16);
  *(uint4*)(lds + sc * 32 + 8 * ((w8 >> 3) ^ ((sc >> 1) & 3))) = u;
}

// B-fragment: lane (g,lr) reads B^T[c = nf*16+lr][k = g*8 .. g*8+7]
__device__ __forceinline__ bf16x8 bfrag(const unsigned short* lds, int g, int lr, int nf){
  int c = nf * 16 + lr;
  return ldfrag(lds + c * 32 + 8 * (g ^ ((c >> 1) & 3)));
}

// ---- init ----
__global__ __launch_bounds__(256) void k_init(const float* __restrict__ mw1,
    const float* __restrict__ mw2,
    unsigned short* __restrict__ Awr, unsigned short* __restrict__ Awi,
    unsigned short* __restrict__ Ahc, unsigned short* __restrict__ Ahs,
    unsigned short* __restrict__ Air, unsigned short* __restrict__ Aii,
    unsigned short* __restrict__ w1s, unsigned short* __restrict__ w2c){
  int i = blockIdx.x * 256 + threadIdx.x;            // < 262144
  if (i < 49152) {                                   // Aw: 192 x 256 (kw padded)
    int m = i >> 8, w = i & 255;
    float t = (float)((m * w) & 255) / 128.0f;
    Awr[i] = f2b(cospif(t) * 0.0625f);
    Awi[i] = f2b(-sinpif(t) * 0.0625f);
  }
  if (i < 65536) {                                   // Ah: 256 x 256
    int k = i >> 8, h = i & 255;
    float t = (float)((k * h) & 255) / 128.0f;
    Ahc[i] = f2b(cospif(t) * 0.0625f);
    Ahs[i] = f2b(sinpif(t) * 0.0625f);
  }
  if (i < 32768) {                                   // Awinv: 256(w) x 128(kw), c_k folded
    int w = i >> 7, kw = i & 127;
    float t = (float)((kw * w) & 255) / 128.0f;
    float c = (kw == 0) ? 0.0625f : 0.125f;
    Air[i] = f2b(cospif(t) * c);
    Aii[i] = f2b(-sinpif(t) * c);
  }
  {
    int l = i >> 8, k2 = i & 255;
    w1s[(l << 8) | (k2 ^ ((l & 7) << 3))] = f2b(mw1[k2 * LAT + l]);
    int n = i >> 10, l2 = i & 1023;
    int ch = l2 >> 6, kk = l2 & 63;
    w2c[(size_t)((ch << 8) + n) * 64 + (kk ^ ((n & 7) << 3))] = f2b(mw2[l2 * CC + n]);
  }
}

// ---- LN1: bf16 out only ----
__global__ __launch_bounds__(256) void k_ln1(const float* __restrict__ in,
    const float* __restrict__ g, const float* __restrict__ b,
    unsigned short* __restrict__ outb){
  int lane = threadIdx.x & 63;
  size_t row = (size_t)blockIdx.x * 4 + (threadIdx.x >> 6);
  float4 v = ((const float4*)(in + row * CC))[lane];
  float s = wred(v.x + v.y + v.z + v.w);
  float q = wred(v.x*v.x + v.y*v.y + v.z*v.z + v.w*v.w);
  float mean = s * (1.0f/CC);
  float rstd = rsqrtf(q * (1.0f/CC) - mean*mean + 1e-5f);
  float4 gv = ((const float4*)g)[lane];
  float4 bv = ((const float4*)b)[lane];
  ushort4 ob;
  ob.x = f2b((v.x - mean) * rstd * gv.x + bv.x);
  ob.y = f2b((v.y - mean) * rstd * gv.y + bv.y);
  ob.z = f2b((v.z - mean) * rstd * gv.z + bv.z);
  ob.w = f2b((v.w - mean) * rstd * gv.w + bv.w);
  ((ushort4*)(outb + row * CC))[lane] = ob;
}

// ---- LN2: bf16 in, bf16 out ----
__global__ __launch_bounds__(256) void k_ln2(const unsigned short* __restrict__ in,
    const float* __restrict__ g, const float* __restrict__ b,
    unsigned short* __restrict__ out){
  int lane = threadIdx.x & 63;
  size_t row = (size_t)blockIdx.x * 4 + (threadIdx.x >> 6);
  ushort4 uv = ((const ushort4*)(in + row * CC))[lane];
  float4 v;
  v.x = b2f(uv.x); v.y = b2f(uv.y); v.z = b2f(uv.z); v.w = b2f(uv.w);
  float s = wred(v.x + v.y + v.z + v.w);
  float q = wred(v.x*v.x + v.y*v.y + v.z*v.z + v.w*v.w);
  float mean = s * (1.0f/CC);
  float rstd = rsqrtf(q * (1.0f/CC) - mean*mean + 1e-5f);
  float4 gv = ((const float4*)g)[lane];
  float4 bv = ((const float4*)b)[lane];
  ushort4 o;
  o.x = f2b((v.x - mean) * rstd * gv.x + bv.x);
  o.y = f2b((v.y - mean) * rstd * gv.y + bv.y);
  o.z = f2b((v.z - mean) * rstd * gv.z + bv.z);
  o.w = f2b((v.w - mean) * rstd * gv.w + bv.w);
  ((ushort4*)(out + row * CC))[lane] = o;
}

// ---- W-forward rDFT as MFMA GEMM, double-buffered staging (1 barrier/ks) ----
__global__ __launch_bounds__(256) void k_gw(const unsigned short* __restrict__ h1b,
    const unsigned short* __restrict__ Awr, const unsigned short* __restrict__ Awi,
    unsigned short* __restrict__ Xr, unsigned short* __restrict__ Xi){
  __shared__ __align__(16) unsigned short sb[2][2048];
  int tid = threadIdx.x, wv = tid >> 6, lane = tid & 63, g = lane >> 4, lr = lane & 15;
  int sc = tid & 63, w8 = (tid >> 6) * 8;
  int bh = blockIdx.x, m0 = blockIdx.y * 64, n0 = blockIdx.z * 64;
  const unsigned short* Bsrc = h1b + (size_t)bh * 65536 + n0;
  int arow = m0 + wv * 16 + lr;
  f32x4 aR[4], aI[4];
#pragma unroll
  for (int i = 0; i < 4; ++i) { aR[i] = (f32x4){0,0,0,0}; aI[i] = (f32x4){0,0,0,0}; }
  unsigned short vb[8];
  stage_ld(Bsrc, vb, sc, w8);
  stage_wr(vb, sb[0], sc, w8);
  __syncthreads();
  for (int ks = 0; ks < 8; ++ks) {
    int cur = ks & 1;
    if (ks < 7) stage_ld(Bsrc + (size_t)(ks + 1) * 32 * CC, vb, sc, w8);
    bf16x8 ar = ldfrag(Awr + (size_t)arow * 256 + ks * 32 + g * 8);
    bf16x8 ai = ldfrag(Awi + (size_t)arow * 256 + ks * 32 + g * 8);
#pragma unroll
    for (int nf = 0; nf < 4; ++nf) {
      bf16x8 bf = bfrag(sb[cur], g, lr, nf);
      aR[nf] = __builtin_amdgcn_mfma_f32_16x16x32_bf16(ar, bf, aR[nf], 0, 0, 0);
      aI[nf] = __builtin_amdgcn_mfma_f32_16x16x32_bf16(ai, bf, aI[nf], 0, 0, 0);
    }
    if (ks < 7) {
      stage_wr(vb, sb[cur ^ 1], sc, w8);
      __syncthreads();
    }
  }
  int b = bh >> 8, h = bh & 255;
#pragma unroll
  for (int nf = 0; nf < 4; ++nf) {
    int c = n0 + nf * 16 + lr;
#pragma unroll
    for (int r = 0; r < 4; ++r) {
      int kw = m0 + wv * 16 + g * 4 + r;
      if (kw < KF) {
        size_t o = ((size_t)(b * KF + kw) * 256 + h) * 256 + c;
        Xr[o] = f2b(aR[nf][r]);
        Xi[o] = f2b(aI[nf][r]);
      }
    }
  }
}

// ---- H-direction complex DFT, M-merged x2, double-buffered staging ----
template<int INV>
__global__ __launch_bounds__(256) void k_gh(const unsigned short* __restrict__ Bre,
    const unsigned short* __restrict__ Bim, const unsigned short* __restrict__ Ac,
    const unsigned short* __restrict__ As, unsigned short* __restrict__ Ore,
    unsigned short* __restrict__ Oim){
  __shared__ __align__(16) unsigned short sr[2][2048], si[2][2048];
  int tid = threadIdx.x, wv = tid >> 6, lane = tid & 63, g = lane >> 4, lr = lane & 15;
  int sc = tid & 63, w8 = (tid >> 6) * 8;
  int bkw = blockIdx.x, m0 = blockIdx.y * 128, n0 = blockIdx.z * 64;
  const unsigned short* srcR = Bre + (size_t)bkw * 65536 + n0;
  const unsigned short* srcI = Bim + (size_t)bkw * 65536 + n0;
  f32x4 accR[2][4], accI[2][4];
#pragma unroll
  for (int m = 0; m < 2; ++m)
#pragma unroll
    for (int i = 0; i < 4; ++i) { accR[m][i] = (f32x4){0,0,0,0}; accI[m][i] = (f32x4){0,0,0,0}; }
  unsigned short vr[8], vi[8];
  stage_ld(srcR, vr, sc, w8);
  stage_ld(srcI, vi, sc, w8);
  stage_wr(vr, sr[0], sc, w8);
  stage_wr(vi, si[0], sc, w8);
  __syncthreads();
  for (int ks = 0; ks < 8; ++ks) {
    int cur = ks & 1;
    if (ks < 7) {
      stage_ld(srcR + (size_t)(ks + 1) * 32 * CC, vr, sc, w8);
      stage_ld(srcI + (size_t)(ks + 1) * 32 * CC, vi, sc, w8);
    }
    bf16x8 bR[4], bI[4];
#pragma unroll
    for (int nf = 0; nf < 4; ++nf) { bR[nf] = bfrag(sr[cur], g, lr, nf); bI[nf] = bfrag(si[cur], g, lr, nf); }
#pragma unroll
    for (int mt = 0; mt < 2; ++mt) {
      int arow = m0 + mt * 64 + wv * 16 + lr;
      bf16x8 ac = ldfrag(Ac + (size_t)arow * 256 + ks * 32 + g * 8);
      bf16x8 as = ldfrag(As + (size_t)arow * 256 + ks * 32 + g * 8);
      bf16x8 asn = negf(as);
#pragma unroll
      for (int nf = 0; nf < 4; ++nf) {
        accR[mt][nf] = __builtin_amdgcn_mfma_f32_16x16x32_bf16(ac, bR[nf], accR[mt][nf], 0, 0, 0);
        accR[mt][nf] = __builtin_amdgcn_mfma_f32_16x16x32_bf16(INV ? asn : as, bI[nf], accR[mt][nf], 0, 0, 0);
        accI[mt][nf] = __builtin_amdgcn_mfma_f32_16x16x32_bf16(ac, bI[nf], accI[mt][nf], 0, 0, 0);
        accI[mt][nf] = __builtin_amdgcn_mfma_f32_16x16x32_bf16(INV ? as : asn, bR[nf], accI[mt][nf], 0, 0, 0);
      }
    }
    if (ks < 7) {
      stage_wr(vr, sr[cur ^ 1], sc, w8);
      stage_wr(vi, si[cur ^ 1], sc, w8);
      __syncthreads();
    }
  }
  if (!INV) {
#pragma unroll
    for (int mt = 0; mt < 2; ++mt)
#pragma unroll
      for (int nf = 0; nf < 4; ++nf) {
        int c = n0 + nf * 16 + lr;
#pragma unroll
        for (int r = 0; r < 4; ++r) {
          int kh = m0 + mt * 64 + wv * 16 + g * 4 + r;
          size_t o = ((size_t)bkw * 256 + kh) * 256 + c;
          Ore[o] = f2b(accR[mt][nf][r]);
          Oim[o] = f2b(accI[mt][nf][r]);
        }
      }
  } else {
    int b = (bkw >= KF) ? 1 : 0;
    int kw = bkw - b * KF;
#pragma unroll
    for (int mt = 0; mt < 2; ++mt)
#pragma unroll
      for (int nf = 0; nf < 4; ++nf) {
        int c = n0 + nf * 16 + lr;
#pragma unroll
        for (int r = 0; r < 4; ++r) {
          int h = m0 + mt * 64 + wv * 16 + g * 4 + r;
          size_t o = (((size_t)b * 256 + h) * KF + kw) * 256 + c;
          Ore[o] = f2b(accR[mt][nf][r]);
          Oim[o] = f2b(accI[mt][nf][r]);
        }
      }
  }
}

// ---- W-inverse rDFT + Nyquist + residuals, M-merged x2; out1 stored bf16 ----
__global__ __launch_bounds__(256) void k_gwi(const unsigned short* __restrict__ Zr,
    const unsigned short* __restrict__ Zi, const unsigned short* __restrict__ Ar,
    const unsigned short* __restrict__ Ai, const float* __restrict__ x,
    const unsigned short* __restrict__ h1b, unsigned short* __restrict__ out1b){
  __shared__ __align__(16) unsigned short sr[2][2048], si[2][2048];
  int tid = threadIdx.x, wv = tid >> 6, lane = tid & 63, g = lane >> 4, lr = lane & 15;
  int sc = tid & 63, w8 = (tid >> 6) * 8;
  int bh = blockIdx.x, m0 = blockIdx.y * 128, n0 = blockIdx.z * 64;
  const unsigned short* srcR = Zr + (size_t)bh * 33024 + n0;
  const unsigned short* srcI = Zi + (size_t)bh * 33024 + n0;
  f32x4 acc[2][4];
#pragma unroll
  for (int m = 0; m < 2; ++m)
#pragma unroll
    for (int i = 0; i < 4; ++i) acc[m][i] = (f32x4){0,0,0,0};
  unsigned short vr[8], vi[8];
  stage_ld(srcR, vr, sc, w8);
  stage_ld(srcI, vi, sc, w8);
  stage_wr(vr, sr[0], sc, w8);
  stage_wr(vi, si[0], sc, w8);
  __syncthreads();
  for (int ks = 0; ks < 4; ++ks) {
    int cur = ks & 1;
    if (ks < 3) {
      stage_ld(srcR + (size_t)(ks + 1) * 32 * CC, vr, sc, w8);
      stage_ld(srcI + (size_t)(ks + 1) * 32 * CC, vi, sc, w8);
    }
    bf16x8 bR[4], bI[4];
#pragma unroll
    for (int nf = 0; nf < 4; ++nf) { bR[nf] = bfrag(sr[cur], g, lr, nf); bI[nf] = bfrag(si[cur], g, lr, nf); }
#pragma unroll
    for (int mt = 0; mt < 2; ++mt) {
      int arow = m0 + mt * 64 + wv * 16 + lr;
      bf16x8 ar = ldfrag(Ar + (size_t)arow * 128 + ks * 32 + g * 8);
      bf16x8 ai = ldfrag(Ai + (size_t)arow * 128 + ks * 32 + g * 8);
#pragma unroll
      for (int nf = 0; nf < 4; ++nf) {
        acc[mt][nf] = __builtin_amdgcn_mfma_f32_16x16x32_bf16(ar, bR[nf], acc[mt][nf], 0, 0, 0);
        acc[mt][nf] = __builtin_amdgcn_mfma_f32_16x16x32_bf16(ai, bI[nf], acc[mt][nf], 0, 0, 0);
      }
    }
    if (ks < 3) {
      stage_wr(vr, sr[cur ^ 1], sc, w8);
      stage_wr(vi, si[cur ^ 1], sc, w8);
      __syncthreads();
    }
  }
#pragma unroll
  for (int nf = 0; nf < 4; ++nf) {
    int c = n0 + nf * 16 + lr;
    float zn = b2f(Zr[(size_t)bh * 33024 + 32768 + c]) * 0.0625f;  // kw=128, sin=0
#pragma unroll
    for (int mt = 0; mt < 2; ++mt)
#pragma unroll
      for (int r = 0; r < 4; ++r) {
        int w = m0 + mt * 64 + wv * 16 + g * 4 + r;
        size_t idx = ((size_t)bh * 256 + w) * 256 + c;
        float ny = (w & 1) ? -zn : zn;
        out1b[idx] = f2b(acc[mt][nf][r] + ny + b2f(h1b[idx]) + x[idx]);
      }
  }
}

// ---- block-diagonal complex MLP: 16 positions/block, weights reg-cached ----
__global__ __launch_bounds__(256) void k_bmlp(const unsigned short* __restrict__ Yr,
    const unsigned short* __restrict__ Yi, const float* __restrict__ w1,
    const float* __restrict__ b1, const float* __restrict__ w2,
    const float* __restrict__ b2, unsigned short* __restrict__ Or,
    unsigned short* __restrict__ Oi){
  __shared__ unsigned short sx[2][16][256];   // r/i, pos, chan (16 KB)
  __shared__ unsigned short s1[2][16][256];   // relu(o1) bf16  (16 KB)
  int tid = threadIdx.x;
  int n = tid >> 5, o = tid & 31;
  size_t pos0 = (size_t)blockIdx.x * 16;
  {
    int p = tid >> 4, cb = (tid & 15) * 16;
#pragma unroll
    for (int q = 0; q < 2; ++q) {
      *(uint4*)&sx[0][p][cb + q * 8] = *(const uint4*)(Yr + (pos0 + p) * CC + cb + q * 8);
      *(uint4*)&sx[1][p][cb + q * 8] = *(const uint4*)(Yi + (pos0 + p) * CC + cb + q * 8);
    }
  }
  // register-cache this thread's weight columns (f32, exact)
  float w1r[32], w1i[32], w2r[32], w2i[32];
#pragma unroll
  for (int i = 0; i < 32; ++i) {
    w1r[i] = w1[(n * BSZ + i) * BSZ + o];
    w1i[i] = w1[NBK * BSZ * BSZ + (n * BSZ + i) * BSZ + o];
    w2r[i] = w2[(n * BSZ + i) * BSZ + o];
    w2i[i] = w2[NBK * BSZ * BSZ + (n * BSZ + i) * BSZ + o];
  }
  float br = b1[n * BSZ + o], bi = b1[NBK * BSZ + n * BSZ + o];
  float cr = b2[n * BSZ + o], ci = b2[NBK * BSZ + n * BSZ + o];
  __syncthreads();
  for (int pt = 0; pt < 4; ++pt) {
    float a1r[4], a1i[4];
#pragma unroll
    for (int p = 0; p < 4; ++p) { a1r[p] = br; a1i[p] = bi; }
#pragma unroll
    for (int i = 0; i < 32; ++i) {
#pragma unroll
      for (int p = 0; p < 4; ++p) {
        float xr = b2f(sx[0][pt * 4 + p][n * BSZ + i]);
        float xi = b2f(sx[1][pt * 4 + p][n * BSZ + i]);
        a1r[p] += xr * w1r[i] - xi * w1i[i];
        a1i[p] += xi * w1r[i] + xr * w1i[i];
      }
    }
#pragma unroll
    for (int p = 0; p < 4; ++p) {
      s1[0][pt * 4 + p][n * BSZ + o] = f2b(fmaxf(a1r[p], 0.f));
      s1[1][pt * 4 + p][n * BSZ + o] = f2b(fmaxf(a1i[p], 0.f));
    }
  }
  __syncthreads();
  for (int pt = 0; pt < 4; ++pt) {
    float a2r[4], a2i[4];
#pragma unroll
    for (int p = 0; p < 4; ++p) { a2r[p] = cr; a2i[p] = ci; }
#pragma unroll
    for (int i = 0; i < 32; ++i) {
#pragma unroll
      for (int p = 0; p < 4; ++p) {
        float xr = b2f(s1[0][pt * 4 + p][n * BSZ + i]);
        float xi = b2f(s1[1][pt * 4 + p][n * BSZ + i]);
        a2r[p] += xr * w2r[i] - xi * w2i[i];
        a2i[p] += xi * w2r[i] + xr * w2i[i];
      }
    }
#pragma unroll
    for (int p = 0; p < 4; ++p) {
      float vr = a2r[p], vi = a2i[p];
      size_t idx = (pos0 + pt * 4 + p) * CC + n * BSZ + o;
      Or[idx] = f2b((fabsf(vr) > 0.01f) ? (vr - copysignf(0.01f, vr)) : 0.f);
      Oi[idx] = f2b((fabsf(vi) > 0.01f) ? (vi - copysignf(0.01f, vi)) : 0.f);
    }
  }
}

// ---- fused MLP: round-10 verified structure (stage-2 N-split, sw2 staged) ----
__global__ __launch_bounds__(256, 2) void k_mlp(const unsigned short* __restrict__ h2,
    const unsigned short* __restrict__ w1s, const float* __restrict__ mb1,
    const unsigned short* __restrict__ w2c, const float* __restrict__ mb2,
    const unsigned short* __restrict__ residb, float* __restrict__ out){
  __shared__ __align__(16) unsigned short sw1[64 * 256];   // [l_local][k ^ ((l&7)<<3)]
  __shared__ __align__(16) unsigned short sw2[256 * 64];   // [n][kk ^ ((n&7)<<3)]
  __shared__ __align__(16) unsigned short mids[64][64];    // [row][e ^ ((row&7)<<3)]
  int tid = threadIdx.x;
  int wave = tid >> 6, lane = tid & 63;
  int g = lane >> 4, lr = lane & 15;
  size_t row0 = (size_t)blockIdx.x * 64;
  bf16x8 areg[8];
#pragma unroll
  for (int ks = 0; ks < 8; ++ks)
    areg[ks] = ldfrag(h2 + (row0 + wave * 16 + lr) * CC + ks * 32 + g * 8);
  f32x4 acc2[4][4];      // [m-frag][n-frag]; wave owns cols [wave*64, wave*64+64)
#pragma unroll
  for (int mi = 0; mi < 4; ++mi)
#pragma unroll
    for (int ni = 0; ni < 4; ++ni) acc2[mi][ni] = (f32x4){0.f, 0.f, 0.f, 0.f};
  for (int ch = 0; ch < 16; ++ch) {
    __syncthreads();
    {
      const uint4* s1 = (const uint4*)(w1s + (size_t)ch * 64 * 256);
      const uint4* s2 = (const uint4*)(w2c + (size_t)ch * 256 * 64);
      uint4* d1 = (uint4*)sw1;
      uint4* d2 = (uint4*)sw2;
#pragma unroll
      for (int it = 0; it < 8; ++it) d1[it * 256 + tid] = s1[it * 256 + tid];
#pragma unroll
      for (int it = 0; it < 8; ++it) d2[it * 256 + tid] = s2[it * 256 + tid];
    }
    __syncthreads();
    // stage 1: wave computes its 16 rows x 64 latent (4 indep chains)
    f32x4 acc1[4];
#pragma unroll
    for (int s = 0; s < 4; ++s) acc1[s] = (f32x4){0.f, 0.f, 0.f, 0.f};
#pragma unroll
    for (int ks = 0; ks < 8; ++ks) {
#pragma unroll
      for (int s = 0; s < 4; ++s) {
        int l = s * 16 + lr;
        bf16x8 bf = ldfrag(sw1 + l * 256 + ((ks * 32 + g * 8) ^ ((lr & 7) << 3)));
        acc1[s] = __builtin_amdgcn_mfma_f32_16x16x32_bf16(areg[ks], bf, acc1[s], 0, 0, 0);
      }
    }
    int l0 = ch * 64;
#pragma unroll
    for (int s = 0; s < 4; ++s) {
      float bias = mb1[l0 + s * 16 + lr];
#pragma unroll
      for (int r = 0; r < 4; ++r) {
        int row = wave * 16 + g * 4 + r;
        mids[row][(s * 16 + lr) ^ ((row & 7) << 3)] = f2b(gelu_t(acc1[s][r] + bias));
      }
    }
    __syncthreads();   // mids visible to all waves
    // stage 2: wave computes all 64 rows x its 64-col slice
#pragma unroll
    for (int ks = 0; ks < 2; ++ks) {
      bf16x8 af[4], bfv[4];
#pragma unroll
      for (int mi = 0; mi < 4; ++mi)
        af[mi] = ldfrag(&mids[mi * 16 + lr][(ks * 32 + g * 8) ^ ((lr & 7) << 3)]);
#pragma unroll
      for (int ni = 0; ni < 4; ++ni)
        bfv[ni] = ldfrag(sw2 + (wave * 64 + ni * 16 + lr) * 64 + ((ks * 32 + g * 8) ^ ((lr & 7) << 3)));
#pragma unroll
      for (int mi = 0; mi < 4; ++mi)
#pragma unroll
        for (int ni = 0; ni < 4; ++ni)
          acc2[mi][ni] = __builtin_amdgcn_mfma_f32_16x16x32_bf16(af[mi], bfv[ni], acc2[mi][ni], 0, 0, 0);
    }
  }
#pragma unroll
  for (int mi = 0; mi < 4; ++mi)
#pragma unroll
    for (int ni = 0; ni < 4; ++ni) {
      int n = wave * 64 + ni * 16 + lr;
      float bias = mb2[n];
#pragma unroll
      for (int r = 0; r < 4; ++r) {
        size_t idx = (row0 + mi * 16 + g * 4 + r) * CC + n;
        out[idx] = acc2[mi][ni][r] + bias + b2f(residb[idx]);
      }
    }
}

extern "C" void kernel_launch(void* const* d_in, const int* in_sizes, int n_in,
                              void* d_out, int out_size, void* d_ws, size_t ws_size,
                              hipStream_t stream) {
  const float* x   = (const float*)d_in[0];
  const float* n1g = (const float*)d_in[1];
  const float* n1b = (const float*)d_in[2];
  const float* n2g = (const float*)d_in[3];
  const float* n2b = (const float*)d_in[4];
  const float* w1  = (const float*)d_in[5];
  const float* b1  = (const float*)d_in[6];
  const float* w2  = (const float*)d_in[7];
  const float* b2  = (const float*)d_in[8];
  const float* mw1 = (const float*)d_in[9];
  const float* mb1 = (const float*)d_in[10];
  const float* mw2 = (const float*)d_in[11];
  const float* mb2 = (const float*)d_in[12];
  float* out = (float*)d_out;

  char* ws = (char*)d_ws;
  unsigned short* o1b = (unsigned short*)(ws);                // out1 bf16, 67,108,864 B
  unsigned short* h1b = (unsigned short*)(ws + 134217728ull); // 67,108,864 B; later h2b
  unsigned short* Xr  = (unsigned short*)(ws + 201326592ull); // 33,816,576 B (also O_r)
  unsigned short* Xi  = (unsigned short*)(ws + 235143168ull); // 33,816,576 B (also O_i)
  unsigned short* Yr  = (unsigned short*)(ws + 268959744ull); // 33,816,576 B (also Z_r)
  unsigned short* Yi  = (unsigned short*)(ws + 302776320ull); // 33,816,576 B (also Z_i)
  unsigned short* Awr = (unsigned short*)(ws + 336592896ull); // 98,304 B
  unsigned short* Awi = (unsigned short*)(ws + 336691200ull); // 98,304 B
  unsigned short* Ahc = (unsigned short*)(ws + 336789504ull); // 131,072 B
  unsigned short* Ahs = (unsigned short*)(ws + 336920576ull); // 131,072 B
  unsigned short* Air = (unsigned short*)(ws + 337051648ull); // 65,536 B
  unsigned short* Aii = (unsigned short*)(ws + 337117184ull); // 65,536 B
  unsigned short* w1s = (unsigned short*)(ws + 337182720ull); // 524,288 B
  unsigned short* w2c = (unsigned short*)(ws + 337707008ull); // 524,288 B

  k_init<<<1024, 256, 0, stream>>>(mw1, mw2, Awr, Awi, Ahc, Ahs, Air, Aii, w1s, w2c);
  k_ln1<<<32768, 256, 0, stream>>>(x, n1g, n1b, h1b);
  k_gw<<<dim3(512, 3, 4), 256, 0, stream>>>(h1b, Awr, Awi, Xr, Xi);
  k_gh<0><<<dim3(258, 2, 4), 256, 0, stream>>>(Xr, Xi, Ahc, Ahs, Yr, Yi);
  k_bmlp<<<4128, 256, 0, stream>>>(Yr, Yi, w1, b1, w2, b2, Xr, Xi);
  k_gh<1><<<dim3(258, 2, 4), 256, 0, stream>>>(Xr, Xi, Ahc, Ahs, Yr, Yi);
  k_gwi<<<dim3(512, 2, 4), 256, 0, stream>>>(Yr, Yi, Air, Aii, x, h1b, o1b);
  k_ln2<<<32768, 256, 0, stream>>>(o1b, n2g, n2b, h1b);
  k_mlp<<<2048, 256, 0, stream>>>(h1b, w1s, mb1, w2c, mb2, o1b, out);
}

// Round 16
// 652.930 us; speedup vs baseline: 1.5290x; 1.2426x over previous
//
#include <hip/hip_runtime.h>
#include <math.h>

#define CC 256
#define KF 129
#define NBK 8
#define BSZ 32
#define LAT 1024

typedef __attribute__((ext_vector_type(8))) __bf16 bf16x8;
typedef __attribute__((ext_vector_type(4))) float f32x4;
typedef __attribute__((ext_vector_type(4))) unsigned u32x4;

__device__ __forceinline__ float wred(float v){
#pragma unroll
  for (int o = 32; o; o >>= 1) v += __shfl_xor(v, o, 64);
  return v;
}

// f32 -> bf16 bits, round-to-nearest-even
__device__ __forceinline__ unsigned short f2b(float f){
  unsigned u = __builtin_bit_cast(unsigned, f);
  unsigned r = u + 0x7fffu + ((u >> 16) & 1u);
  return (unsigned short)(r >> 16);
}
__device__ __forceinline__ float b2f(unsigned short h){
  unsigned u = ((unsigned)h) << 16;
  return __builtin_bit_cast(float, u);
}

__device__ __forceinline__ bf16x8 ldfrag(const unsigned short* p){
  return __builtin_bit_cast(bf16x8, *(const uint4*)p);
}
__device__ __forceinline__ bf16x8 negf(bf16x8 v){
  u32x4 u = __builtin_bit_cast(u32x4, v);
  u = u ^ 0x80008000u;
  return __builtin_bit_cast(bf16x8, u);
}

// tanh-form GELU
__device__ __forceinline__ float gelu_t(float v){
  float s = v * v;
  float t = v * fmaf(s, -0.0713575f, -1.5957691f);   // -z
  float e = __expf(t);                                // e^{-z}
  return v * __builtin_amdgcn_rcpf(1.0f + e);
}

// ---- staging split for double-buffer: load 8 u16 (one c, 8 k's) / pack+write ----
__device__ __forceinline__ void stage_ld(const unsigned short* __restrict__ gp,
    unsigned short* v, int sc, int w8){
#pragma unroll
  for (int j = 0; j < 8; ++j) v[j] = gp[(size_t)(w8 + j) * CC + sc];
}
__device__ __forceinline__ void stage_wr(const unsigned short* v,
    unsigned short* lds, int sc, int w8){
  uint4 u;
  u.x = (unsigned)v[0] | ((unsigned)v[1] << 16);
  u.y = (unsigned)v[2] | ((unsigned)v[3] << 16);
  u.z = (unsigned)v[4] | ((unsigned)v[5] << 16);
  u.w = (unsigned)v[6] | ((unsigned)v[7] << 16);
  *(uint4*)(lds + sc * 32 + 8 * ((w8 >> 3) ^ ((sc >> 1) & 3))) = u;
}

// B-fragment: lane (g,lr) reads B^T[c = nf*16+lr][k = g*8 .. g*8+7]
__device__ __forceinline__ bf16x8 bfrag(const unsigned short* lds, int g, int lr, int nf){
  int c = nf * 16 + lr;
  return ldfrag(lds + c * 32 + 8 * (g ^ ((c >> 1) & 3)));
}

// ---- init: twiddles + mlp weights + TRANSPOSED bf16 bmlp weight tables ----
__global__ __launch_bounds__(256) void k_init(const float* __restrict__ mw1,
    const float* __restrict__ mw2, const float* __restrict__ w1,
    const float* __restrict__ w2,
    unsigned short* __restrict__ Awr, unsigned short* __restrict__ Awi,
    unsigned short* __restrict__ Ahc, unsigned short* __restrict__ Ahs,
    unsigned short* __restrict__ Air, unsigned short* __restrict__ Aii,
    unsigned short* __restrict__ w1s, unsigned short* __restrict__ w2c,
    unsigned short* __restrict__ w1tr, unsigned short* __restrict__ w1ti,
    unsigned short* __restrict__ w2tr, unsigned short* __restrict__ w2ti){
  int i = blockIdx.x * 256 + threadIdx.x;            // < 262144
  if (i < 49152) {                                   // Aw: 192 x 256 (kw padded)
    int m = i >> 8, w = i & 255;
    float t = (float)((m * w) & 255) / 128.0f;
    Awr[i] = f2b(cospif(t) * 0.0625f);
    Awi[i] = f2b(-sinpif(t) * 0.0625f);
  }
  if (i < 65536) {                                   // Ah: 256 x 256
    int k = i >> 8, h = i & 255;
    float t = (float)((k * h) & 255) / 128.0f;
    Ahc[i] = f2b(cospif(t) * 0.0625f);
    Ahs[i] = f2b(sinpif(t) * 0.0625f);
  }
  if (i < 32768) {                                   // Awinv: 256(w) x 128(kw), c_k folded
    int w = i >> 7, kw = i & 127;
    float t = (float)((kw * w) & 255) / 128.0f;
    float c = (kw == 0) ? 0.0625f : 0.125f;
    Air[i] = f2b(cospif(t) * c);
    Aii[i] = f2b(-sinpif(t) * c);
  }
  if (i < 8192) {                                    // bmlp W^T: [n][o][i] = w[n][i][o]
    int n = i >> 10, o = (i >> 5) & 31, ii = i & 31;
    int src = (n * BSZ + ii) * BSZ + o;
    w1tr[i] = f2b(w1[src]);
    w1ti[i] = f2b(w1[NBK * BSZ * BSZ + src]);
    w2tr[i] = f2b(w2[src]);
    w2ti[i] = f2b(w2[NBK * BSZ * BSZ + src]);
  }
  {
    int l = i >> 8, k2 = i & 255;
    w1s[(l << 8) | (k2 ^ ((l & 7) << 3))] = f2b(mw1[k2 * LAT + l]);
    int n = i >> 10, l2 = i & 1023;
    int ch = l2 >> 6, kk = l2 & 63;
    w2c[(size_t)((ch << 8) + n) * 64 + (kk ^ ((n & 7) << 3))] = f2b(mw2[l2 * CC + n]);
  }
}

// ---- LN1: bf16 out only ----
__global__ __launch_bounds__(256) void k_ln1(const float* __restrict__ in,
    const float* __restrict__ g, const float* __restrict__ b,
    unsigned short* __restrict__ outb){
  int lane = threadIdx.x & 63;
  size_t row = (size_t)blockIdx.x * 4 + (threadIdx.x >> 6);
  float4 v = ((const float4*)(in + row * CC))[lane];
  float s = wred(v.x + v.y + v.z + v.w);
  float q = wred(v.x*v.x + v.y*v.y + v.z*v.z + v.w*v.w);
  float mean = s * (1.0f/CC);
  float rstd = rsqrtf(q * (1.0f/CC) - mean*mean + 1e-5f);
  float4 gv = ((const float4*)g)[lane];
  float4 bv = ((const float4*)b)[lane];
  ushort4 ob;
  ob.x = f2b((v.x - mean) * rstd * gv.x + bv.x);
  ob.y = f2b((v.y - mean) * rstd * gv.y + bv.y);
  ob.z = f2b((v.z - mean) * rstd * gv.z + bv.z);
  ob.w = f2b((v.w - mean) * rstd * gv.w + bv.w);
  ((ushort4*)(outb + row * CC))[lane] = ob;
}

// ---- LN2: bf16 in, bf16 out ----
__global__ __launch_bounds__(256) void k_ln2(const unsigned short* __restrict__ in,
    const float* __restrict__ g, const float* __restrict__ b,
    unsigned short* __restrict__ out){
  int lane = threadIdx.x & 63;
  size_t row = (size_t)blockIdx.x * 4 + (threadIdx.x >> 6);
  ushort4 uv = ((const ushort4*)(in + row * CC))[lane];
  float4 v;
  v.x = b2f(uv.x); v.y = b2f(uv.y); v.z = b2f(uv.z); v.w = b2f(uv.w);
  float s = wred(v.x + v.y + v.z + v.w);
  float q = wred(v.x*v.x + v.y*v.y + v.z*v.z + v.w*v.w);
  float mean = s * (1.0f/CC);
  float rstd = rsqrtf(q * (1.0f/CC) - mean*mean + 1e-5f);
  float4 gv = ((const float4*)g)[lane];
  float4 bv = ((const float4*)b)[lane];
  ushort4 o;
  o.x = f2b((v.x - mean) * rstd * gv.x + bv.x);
  o.y = f2b((v.y - mean) * rstd * gv.y + bv.y);
  o.z = f2b((v.z - mean) * rstd * gv.z + bv.z);
  o.w = f2b((v.w - mean) * rstd * gv.w + bv.w);
  ((ushort4*)(out + row * CC))[lane] = o;
}

// ---- W-forward rDFT as MFMA GEMM, double-buffered staging ----
__global__ __launch_bounds__(256) void k_gw(const unsigned short* __restrict__ h1b,
    const unsigned short* __restrict__ Awr, const unsigned short* __restrict__ Awi,
    unsigned short* __restrict__ Xr, unsigned short* __restrict__ Xi){
  __shared__ __align__(16) unsigned short sb[2][2048];
  int tid = threadIdx.x, wv = tid >> 6, lane = tid & 63, g = lane >> 4, lr = lane & 15;
  int sc = tid & 63, w8 = (tid >> 6) * 8;
  int bh = blockIdx.x, m0 = blockIdx.y * 64, n0 = blockIdx.z * 64;
  const unsigned short* Bsrc = h1b + (size_t)bh * 65536 + n0;
  int arow = m0 + wv * 16 + lr;
  f32x4 aR[4], aI[4];
#pragma unroll
  for (int i = 0; i < 4; ++i) { aR[i] = (f32x4){0,0,0,0}; aI[i] = (f32x4){0,0,0,0}; }
  unsigned short vb[8];
  stage_ld(Bsrc, vb, sc, w8);
  stage_wr(vb, sb[0], sc, w8);
  __syncthreads();
  for (int ks = 0; ks < 8; ++ks) {
    int cur = ks & 1;
    if (ks < 7) stage_ld(Bsrc + (size_t)(ks + 1) * 32 * CC, vb, sc, w8);
    bf16x8 ar = ldfrag(Awr + (size_t)arow * 256 + ks * 32 + g * 8);
    bf16x8 ai = ldfrag(Awi + (size_t)arow * 256 + ks * 32 + g * 8);
#pragma unroll
    for (int nf = 0; nf < 4; ++nf) {
      bf16x8 bf = bfrag(sb[cur], g, lr, nf);
      aR[nf] = __builtin_amdgcn_mfma_f32_16x16x32_bf16(ar, bf, aR[nf], 0, 0, 0);
      aI[nf] = __builtin_amdgcn_mfma_f32_16x16x32_bf16(ai, bf, aI[nf], 0, 0, 0);
    }
    if (ks < 7) {
      stage_wr(vb, sb[cur ^ 1], sc, w8);
      __syncthreads();
    }
  }
  int b = bh >> 8, h = bh & 255;
#pragma unroll
  for (int nf = 0; nf < 4; ++nf) {
    int c = n0 + nf * 16 + lr;
#pragma unroll
    for (int r = 0; r < 4; ++r) {
      int kw = m0 + wv * 16 + g * 4 + r;
      if (kw < KF) {
        size_t o = ((size_t)(b * KF + kw) * 256 + h) * 256 + c;
        Xr[o] = f2b(aR[nf][r]);
        Xi[o] = f2b(aI[nf][r]);
      }
    }
  }
}

// ---- H-direction complex DFT, M-merged x2, double-buffered staging ----
template<int INV>
__global__ __launch_bounds__(256) void k_gh(const unsigned short* __restrict__ Bre,
    const unsigned short* __restrict__ Bim, const unsigned short* __restrict__ Ac,
    const unsigned short* __restrict__ As, unsigned short* __restrict__ Ore,
    unsigned short* __restrict__ Oim){
  __shared__ __align__(16) unsigned short sr[2][2048], si[2][2048];
  int tid = threadIdx.x, wv = tid >> 6, lane = tid & 63, g = lane >> 4, lr = lane & 15;
  int sc = tid & 63, w8 = (tid >> 6) * 8;
  int bkw = blockIdx.x, m0 = blockIdx.y * 128, n0 = blockIdx.z * 64;
  const unsigned short* srcR = Bre + (size_t)bkw * 65536 + n0;
  const unsigned short* srcI = Bim + (size_t)bkw * 65536 + n0;
  f32x4 accR[2][4], accI[2][4];
#pragma unroll
  for (int m = 0; m < 2; ++m)
#pragma unroll
    for (int i = 0; i < 4; ++i) { accR[m][i] = (f32x4){0,0,0,0}; accI[m][i] = (f32x4){0,0,0,0}; }
  unsigned short vr[8], vi[8];
  stage_ld(srcR, vr, sc, w8);
  stage_ld(srcI, vi, sc, w8);
  stage_wr(vr, sr[0], sc, w8);
  stage_wr(vi, si[0], sc, w8);
  __syncthreads();
  for (int ks = 0; ks < 8; ++ks) {
    int cur = ks & 1;
    if (ks < 7) {
      stage_ld(srcR + (size_t)(ks + 1) * 32 * CC, vr, sc, w8);
      stage_ld(srcI + (size_t)(ks + 1) * 32 * CC, vi, sc, w8);
    }
    bf16x8 bR[4], bI[4];
#pragma unroll
    for (int nf = 0; nf < 4; ++nf) { bR[nf] = bfrag(sr[cur], g, lr, nf); bI[nf] = bfrag(si[cur], g, lr, nf); }
#pragma unroll
    for (int mt = 0; mt < 2; ++mt) {
      int arow = m0 + mt * 64 + wv * 16 + lr;
      bf16x8 ac = ldfrag(Ac + (size_t)arow * 256 + ks * 32 + g * 8);
      bf16x8 as = ldfrag(As + (size_t)arow * 256 + ks * 32 + g * 8);
      bf16x8 asn = negf(as);
#pragma unroll
      for (int nf = 0; nf < 4; ++nf) {
        accR[mt][nf] = __builtin_amdgcn_mfma_f32_16x16x32_bf16(ac, bR[nf], accR[mt][nf], 0, 0, 0);
        accR[mt][nf] = __builtin_amdgcn_mfma_f32_16x16x32_bf16(INV ? asn : as, bI[nf], accR[mt][nf], 0, 0, 0);
        accI[mt][nf] = __builtin_amdgcn_mfma_f32_16x16x32_bf16(ac, bI[nf], accI[mt][nf], 0, 0, 0);
        accI[mt][nf] = __builtin_amdgcn_mfma_f32_16x16x32_bf16(INV ? as : asn, bR[nf], accI[mt][nf], 0, 0, 0);
      }
    }
    if (ks < 7) {
      stage_wr(vr, sr[cur ^ 1], sc, w8);
      stage_wr(vi, si[cur ^ 1], sc, w8);
      __syncthreads();
    }
  }
  if (!INV) {
#pragma unroll
    for (int mt = 0; mt < 2; ++mt)
#pragma unroll
      for (int nf = 0; nf < 4; ++nf) {
        int c = n0 + nf * 16 + lr;
#pragma unroll
        for (int r = 0; r < 4; ++r) {
          int kh = m0 + mt * 64 + wv * 16 + g * 4 + r;
          size_t o = ((size_t)bkw * 256 + kh) * 256 + c;
          Ore[o] = f2b(accR[mt][nf][r]);
          Oim[o] = f2b(accI[mt][nf][r]);
        }
      }
  } else {
    int b = (bkw >= KF) ? 1 : 0;
    int kw = bkw - b * KF;
#pragma unroll
    for (int mt = 0; mt < 2; ++mt)
#pragma unroll
      for (int nf = 0; nf < 4; ++nf) {
        int c = n0 + nf * 16 + lr;
#pragma unroll
        for (int r = 0; r < 4; ++r) {
          int h = m0 + mt * 64 + wv * 16 + g * 4 + r;
          size_t o = (((size_t)b * 256 + h) * KF + kw) * 256 + c;
          Ore[o] = f2b(accR[mt][nf][r]);
          Oim[o] = f2b(accI[mt][nf][r]);
        }
      }
  }
}

// ---- W-inverse rDFT + Nyquist + residuals, M-merged x2; out1 stored bf16 ----
__global__ __launch_bounds__(256) void k_gwi(const unsigned short* __restrict__ Zr,
    const unsigned short* __restrict__ Zi, const unsigned short* __restrict__ Ar,
    const unsigned short* __restrict__ Ai, const float* __restrict__ x,
    const unsigned short* __restrict__ h1b, unsigned short* __restrict__ out1b){
  __shared__ __align__(16) unsigned short sr[2][2048], si[2][2048];
  int tid = threadIdx.x, wv = tid >> 6, lane = tid & 63, g = lane >> 4, lr = lane & 15;
  int sc = tid & 63, w8 = (tid >> 6) * 8;
  int bh = blockIdx.x, m0 = blockIdx.y * 128, n0 = blockIdx.z * 64;
  const unsigned short* srcR = Zr + (size_t)bh * 33024 + n0;
  const unsigned short* srcI = Zi + (size_t)bh * 33024 + n0;
  f32x4 acc[2][4];
#pragma unroll
  for (int m = 0; m < 2; ++m)
#pragma unroll
    for (int i = 0; i < 4; ++i) acc[m][i] = (f32x4){0,0,0,0};
  unsigned short vr[8], vi[8];
  stage_ld(srcR, vr, sc, w8);
  stage_ld(srcI, vi, sc, w8);
  stage_wr(vr, sr[0], sc, w8);
  stage_wr(vi, si[0], sc, w8);
  __syncthreads();
  for (int ks = 0; ks < 4; ++ks) {
    int cur = ks & 1;
    if (ks < 3) {
      stage_ld(srcR + (size_t)(ks + 1) * 32 * CC, vr, sc, w8);
      stage_ld(srcI + (size_t)(ks + 1) * 32 * CC, vi, sc, w8);
    }
    bf16x8 bR[4], bI[4];
#pragma unroll
    for (int nf = 0; nf < 4; ++nf) { bR[nf] = bfrag(sr[cur], g, lr, nf); bI[nf] = bfrag(si[cur], g, lr, nf); }
#pragma unroll
    for (int mt = 0; mt < 2; ++mt) {
      int arow = m0 + mt * 64 + wv * 16 + lr;
      bf16x8 ar = ldfrag(Ar + (size_t)arow * 128 + ks * 32 + g * 8);
      bf16x8 ai = ldfrag(Ai + (size_t)arow * 128 + ks * 32 + g * 8);
#pragma unroll
      for (int nf = 0; nf < 4; ++nf) {
        acc[mt][nf] = __builtin_amdgcn_mfma_f32_16x16x32_bf16(ar, bR[nf], acc[mt][nf], 0, 0, 0);
        acc[mt][nf] = __builtin_amdgcn_mfma_f32_16x16x32_bf16(ai, bI[nf], acc[mt][nf], 0, 0, 0);
      }
    }
    if (ks < 3) {
      stage_wr(vr, sr[cur ^ 1], sc, w8);
      stage_wr(vi, si[cur ^ 1], sc, w8);
      __syncthreads();
    }
  }
#pragma unroll
  for (int nf = 0; nf < 4; ++nf) {
    int c = n0 + nf * 16 + lr;
    float zn = b2f(Zr[(size_t)bh * 33024 + 32768 + c]) * 0.0625f;  // kw=128, sin=0
#pragma unroll
    for (int mt = 0; mt < 2; ++mt)
#pragma unroll
      for (int r = 0; r < 4; ++r) {
        int w = m0 + mt * 64 + wv * 16 + g * 4 + r;
        size_t idx = ((size_t)bh * 256 + w) * 256 + c;
        float ny = (w & 1) ? -zn : zn;
        out1b[idx] = f2b(acc[mt][nf][r] + ny + b2f(h1b[idx]) + x[idx]);
      }
  }
}

// ---- block-diagonal complex MLP via MFMA: 64 positions/block, 4 waves x 16 pos,
// sequential over 8 channel-blocks; per-wave mids (no barriers) ----
__global__ __launch_bounds__(256) void k_bmlp(const unsigned short* __restrict__ Yr,
    const unsigned short* __restrict__ Yi,
    const unsigned short* __restrict__ w1tr, const unsigned short* __restrict__ w1ti,
    const unsigned short* __restrict__ w2tr, const unsigned short* __restrict__ w2ti,
    const float* __restrict__ b1, const float* __restrict__ b2,
    unsigned short* __restrict__ Or, unsigned short* __restrict__ Oi){
  __shared__ __align__(16) unsigned short mids[4][16][64];  // [wave][pos][r:0-31|i:32-63], XOR ((pos&7)<<3)
  int tid = threadIdx.x;
  int wave = tid >> 6, lane = tid & 63;
  int g = lane >> 4, lr = lane & 15;
  size_t pos0 = (size_t)blockIdx.x * 64 + wave * 16;
  for (int n = 0; n < NBK; ++n) {
    // layer 1: A = X[pos][i], B = W1^T[o][i]
    bf16x8 axr = ldfrag(Yr + (pos0 + lr) * CC + n * BSZ + g * 8);
    bf16x8 axi = ldfrag(Yi + (pos0 + lr) * CC + n * BSZ + g * 8);
    f32x4 o1r[2], o1i[2];
#pragma unroll
    for (int nf = 0; nf < 2; ++nf) {
      bf16x8 bwr = ldfrag(w1tr + (n * BSZ + nf * 16 + lr) * BSZ + g * 8);
      bf16x8 bwi = ldfrag(w1ti + (n * BSZ + nf * 16 + lr) * BSZ + g * 8);
      f32x4 zr = (f32x4){0,0,0,0}, zi = (f32x4){0,0,0,0};
      zr = __builtin_amdgcn_mfma_f32_16x16x32_bf16(axr, bwr, zr, 0, 0, 0);
      zr = __builtin_amdgcn_mfma_f32_16x16x32_bf16(axi, negf(bwi), zr, 0, 0, 0);
      zi = __builtin_amdgcn_mfma_f32_16x16x32_bf16(axi, bwr, zi, 0, 0, 0);
      zi = __builtin_amdgcn_mfma_f32_16x16x32_bf16(axr, bwi, zi, 0, 0, 0);
      o1r[nf] = zr; o1i[nf] = zi;
    }
    // bias + relu -> bf16 mids (per-wave; wave-synchronous, no barrier)
#pragma unroll
    for (int nf = 0; nf < 2; ++nf) {
      float br = b1[n * BSZ + nf * 16 + lr];
      float bi = b1[NBK * BSZ + n * BSZ + nf * 16 + lr];
#pragma unroll
      for (int r = 0; r < 4; ++r) {
        int row = g * 4 + r;
        int er = nf * 16 + lr;
        mids[wave][row][er ^ ((row & 7) << 3)] = f2b(fmaxf(o1r[nf][r] + br, 0.f));
        mids[wave][row][(32 + er) ^ ((row & 7) << 3)] = f2b(fmaxf(o1i[nf][r] + bi, 0.f));
      }
    }
    // layer 2: A = relu(o1)[pos][i], B = W2^T[o][i]
    bf16x8 par = ldfrag(&mids[wave][lr][(g * 8) ^ ((lr & 7) << 3)]);
    bf16x8 pai = ldfrag(&mids[wave][lr][(32 + g * 8) ^ ((lr & 7) << 3)]);
#pragma unroll
    for (int nf = 0; nf < 2; ++nf) {
      bf16x8 bwr = ldfrag(w2tr + (n * BSZ + nf * 16 + lr) * BSZ + g * 8);
      bf16x8 bwi = ldfrag(w2ti + (n * BSZ + nf * 16 + lr) * BSZ + g * 8);
      f32x4 zr = (f32x4){0,0,0,0}, zi = (f32x4){0,0,0,0};
      zr = __builtin_amdgcn_mfma_f32_16x16x32_bf16(par, bwr, zr, 0, 0, 0);
      zr = __builtin_amdgcn_mfma_f32_16x16x32_bf16(pai, negf(bwi), zr, 0, 0, 0);
      zi = __builtin_amdgcn_mfma_f32_16x16x32_bf16(pai, bwr, zi, 0, 0, 0);
      zi = __builtin_amdgcn_mfma_f32_16x16x32_bf16(par, bwi, zi, 0, 0, 0);
      float cr = b2[n * BSZ + nf * 16 + lr];
      float ci = b2[NBK * BSZ + n * BSZ + nf * 16 + lr];
#pragma unroll
      for (int r = 0; r < 4; ++r) {
        float vr = zr[r] + cr, vi = zi[r] + ci;
        size_t idx = (pos0 + g * 4 + r) * CC + n * BSZ + nf * 16 + lr;
        Or[idx] = f2b((fabsf(vr) > 0.01f) ? (vr - copysignf(0.01f, vr)) : 0.f);
        Oi[idx] = f2b((fabsf(vi) > 0.01f) ? (vi - copysignf(0.01f, vi)) : 0.f);
      }
    }
  }
}

// ---- fused MLP: round-10 verified structure (stage-2 N-split, sw2 staged) ----
__global__ __launch_bounds__(256, 2) void k_mlp(const unsigned short* __restrict__ h2,
    const unsigned short* __restrict__ w1s, const float* __restrict__ mb1,
    const unsigned short* __restrict__ w2c, const float* __restrict__ mb2,
    const unsigned short* __restrict__ residb, float* __restrict__ out){
  __shared__ __align__(16) unsigned short sw1[64 * 256];   // [l_local][k ^ ((l&7)<<3)]
  __shared__ __align__(16) unsigned short sw2[256 * 64];   // [n][kk ^ ((n&7)<<3)]
  __shared__ __align__(16) unsigned short mids[64][64];    // [row][e ^ ((row&7)<<3)]
  int tid = threadIdx.x;
  int wave = tid >> 6, lane = tid & 63;
  int g = lane >> 4, lr = lane & 15;
  size_t row0 = (size_t)blockIdx.x * 64;
  bf16x8 areg[8];
#pragma unroll
  for (int ks = 0; ks < 8; ++ks)
    areg[ks] = ldfrag(h2 + (row0 + wave * 16 + lr) * CC + ks * 32 + g * 8);
  f32x4 acc2[4][4];
#pragma unroll
  for (int mi = 0; mi < 4; ++mi)
#pragma unroll
    for (int ni = 0; ni < 4; ++ni) acc2[mi][ni] = (f32x4){0.f, 0.f, 0.f, 0.f};
  for (int ch = 0; ch < 16; ++ch) {
    __syncthreads();
    {
      const uint4* s1 = (const uint4*)(w1s + (size_t)ch * 64 * 256);
      const uint4* s2 = (const uint4*)(w2c + (size_t)ch * 256 * 64);
      uint4* d1 = (uint4*)sw1;
      uint4* d2 = (uint4*)sw2;
#pragma unroll
      for (int it = 0; it < 8; ++it) d1[it * 256 + tid] = s1[it * 256 + tid];
#pragma unroll
      for (int it = 0; it < 8; ++it) d2[it * 256 + tid] = s2[it * 256 + tid];
    }
    __syncthreads();
    f32x4 acc1[4];
#pragma unroll
    for (int s = 0; s < 4; ++s) acc1[s] = (f32x4){0.f, 0.f, 0.f, 0.f};
#pragma unroll
    for (int ks = 0; ks < 8; ++ks) {
#pragma unroll
      for (int s = 0; s < 4; ++s) {
        int l = s * 16 + lr;
        bf16x8 bf = ldfrag(sw1 + l * 256 + ((ks * 32 + g * 8) ^ ((lr & 7) << 3)));
        acc1[s] = __builtin_amdgcn_mfma_f32_16x16x32_bf16(areg[ks], bf, acc1[s], 0, 0, 0);
      }
    }
    int l0 = ch * 64;
#pragma unroll
    for (int s = 0; s < 4; ++s) {
      float bias = mb1[l0 + s * 16 + lr];
#pragma unroll
      for (int r = 0; r < 4; ++r) {
        int row = wave * 16 + g * 4 + r;
        mids[row][(s * 16 + lr) ^ ((row & 7) << 3)] = f2b(gelu_t(acc1[s][r] + bias));
      }
    }
    __syncthreads();
#pragma unroll
    for (int ks = 0; ks < 2; ++ks) {
      bf16x8 af[4], bfv[4];
#pragma unroll
      for (int mi = 0; mi < 4; ++mi)
        af[mi] = ldfrag(&mids[mi * 16 + lr][(ks * 32 + g * 8) ^ ((lr & 7) << 3)]);
#pragma unroll
      for (int ni = 0; ni < 4; ++ni)
        bfv[ni] = ldfrag(sw2 + (wave * 64 + ni * 16 + lr) * 64 + ((ks * 32 + g * 8) ^ ((lr & 7) << 3)));
#pragma unroll
      for (int mi = 0; mi < 4; ++mi)
#pragma unroll
        for (int ni = 0; ni < 4; ++ni)
          acc2[mi][ni] = __builtin_amdgcn_mfma_f32_16x16x32_bf16(af[mi], bfv[ni], acc2[mi][ni], 0, 0, 0);
    }
  }
#pragma unroll
  for (int mi = 0; mi < 4; ++mi)
#pragma unroll
    for (int ni = 0; ni < 4; ++ni) {
      int n = wave * 64 + ni * 16 + lr;
      float bias = mb2[n];
#pragma unroll
      for (int r = 0; r < 4; ++r) {
        size_t idx = (row0 + mi * 16 + g * 4 + r) * CC + n;
        out[idx] = acc2[mi][ni][r] + bias + b2f(residb[idx]);
      }
    }
}

extern "C" void kernel_launch(void* const* d_in, const int* in_sizes, int n_in,
                              void* d_out, int out_size, void* d_ws, size_t ws_size,
                              hipStream_t stream) {
  const float* x   = (const float*)d_in[0];
  const float* n1g = (const float*)d_in[1];
  const float* n1b = (const float*)d_in[2];
  const float* n2g = (const float*)d_in[3];
  const float* n2b = (const float*)d_in[4];
  const float* w1  = (const float*)d_in[5];
  const float* b1  = (const float*)d_in[6];
  const float* w2  = (const float*)d_in[7];
  const float* b2  = (const float*)d_in[8];
  const float* mw1 = (const float*)d_in[9];
  const float* mb1 = (const float*)d_in[10];
  const float* mw2 = (const float*)d_in[11];
  const float* mb2 = (const float*)d_in[12];
  float* out = (float*)d_out;

  char* ws = (char*)d_ws;
  unsigned short* o1b = (unsigned short*)(ws);                // out1 bf16, 67,108,864 B
  unsigned short* h1b = (unsigned short*)(ws + 134217728ull); // 67,108,864 B; later h2b
  unsigned short* Xr  = (unsigned short*)(ws + 201326592ull); // 33,816,576 B (also O_r)
  unsigned short* Xi  = (unsigned short*)(ws + 235143168ull); // 33,816,576 B (also O_i)
  unsigned short* Yr  = (unsigned short*)(ws + 268959744ull); // 33,816,576 B (also Z_r)
  unsigned short* Yi  = (unsigned short*)(ws + 302776320ull); // 33,816,576 B (also Z_i)
  unsigned short* Awr = (unsigned short*)(ws + 336592896ull); // 98,304 B
  unsigned short* Awi = (unsigned short*)(ws + 336691200ull); // 98,304 B
  unsigned short* Ahc = (unsigned short*)(ws + 336789504ull); // 131,072 B
  unsigned short* Ahs = (unsigned short*)(ws + 336920576ull); // 131,072 B
  unsigned short* Air = (unsigned short*)(ws + 337051648ull); // 65,536 B
  unsigned short* Aii = (unsigned short*)(ws + 337117184ull); // 65,536 B
  unsigned short* w1s = (unsigned short*)(ws + 337182720ull); // 524,288 B
  unsigned short* w2c = (unsigned short*)(ws + 337707008ull); // 524,288 B
  unsigned short* w1tr = (unsigned short*)(ws + 338231296ull); // 16,384 B
  unsigned short* w1ti = (unsigned short*)(ws + 338247680ull); // 16,384 B
  unsigned short* w2tr = (unsigned short*)(ws + 338264064ull); // 16,384 B
  unsigned short* w2ti = (unsigned short*)(ws + 338280448ull); // 16,384 B

  k_init<<<1024, 256, 0, stream>>>(mw1, mw2, w1, w2, Awr, Awi, Ahc, Ahs, Air, Aii,
                                   w1s, w2c, w1tr, w1ti, w2tr, w2ti);
  k_ln1<<<32768, 256, 0, stream>>>(x, n1g, n1b, h1b);
  k_gw<<<dim3(512, 3, 4), 256, 0, stream>>>(h1b, Awr, Awi, Xr, Xi);
  k_gh<0><<<dim3(258, 2, 4), 256, 0, stream>>>(Xr, Xi, Ahc, Ahs, Yr, Yi);
  k_bmlp<<<1032, 256, 0, stream>>>(Yr, Yi, w1tr, w1ti, w2tr, w2ti, b1, b2, Xr, Xi);
  k_gh<1><<<dim3(258, 2, 4), 256, 0, stream>>>(Xr, Xi, Ahc, Ahs, Yr, Yi);
  k_gwi<<<dim3(512, 2, 4), 256, 0, stream>>>(Yr, Yi, Air, Aii, x, h1b, o1b);
  k_ln2<<<32768, 256, 0, stream>>>(o1b, n2g, n2b, h1b);
  k_mlp<<<2048, 256, 0, stream>>>(h1b, w1s, mb1, w2c, mb2, o1b, out);
}

// Round 17
// 630.334 us; speedup vs baseline: 1.5838x; 1.0358x over previous
//
#include <hip/hip_runtime.h>
#include <math.h>

#define CC 256
#define KF 129
#define NBK 8
#define BSZ 32
#define LAT 1024

typedef __attribute__((ext_vector_type(8))) __bf16 bf16x8;
typedef __attribute__((ext_vector_type(4))) float f32x4;
typedef __attribute__((ext_vector_type(4))) unsigned u32x4;

__device__ __forceinline__ float wred(float v){
#pragma unroll
  for (int o = 32; o; o >>= 1) v += __shfl_xor(v, o, 64);
  return v;
}

// f32 -> bf16 bits, round-to-nearest-even
__device__ __forceinline__ unsigned short f2b(float f){
  unsigned u = __builtin_bit_cast(unsigned, f);
  unsigned r = u + 0x7fffu + ((u >> 16) & 1u);
  return (unsigned short)(r >> 16);
}
__device__ __forceinline__ float b2f(unsigned short h){
  unsigned u = ((unsigned)h) << 16;
  return __builtin_bit_cast(float, u);
}

__device__ __forceinline__ bf16x8 ldfrag(const unsigned short* p){
  return __builtin_bit_cast(bf16x8, *(const uint4*)p);
}
__device__ __forceinline__ bf16x8 negf(bf16x8 v){
  u32x4 u = __builtin_bit_cast(u32x4, v);
  u = u ^ 0x80008000u;
  return __builtin_bit_cast(bf16x8, u);
}

// tanh-form GELU
__device__ __forceinline__ float gelu_t(float v){
  float s = v * v;
  float t = v * fmaf(s, -0.0713575f, -1.5957691f);   // -z
  float e = __expf(t);                                // e^{-z}
  return v * __builtin_amdgcn_rcpf(1.0f + e);
}

// ---- staging split for double-buffer: load 8 u16 (one c, 8 k's) / pack+write ----
__device__ __forceinline__ void stage_ld(const unsigned short* __restrict__ gp,
    unsigned short* v, int sc, int w8){
#pragma unroll
  for (int j = 0; j < 8; ++j) v[j] = gp[(size_t)(w8 + j) * CC + sc];
}
__device__ __forceinline__ void stage_wr(const unsigned short* v,
    unsigned short* lds, int sc, int w8){
  uint4 u;
  u.x = (unsigned)v[0] | ((unsigned)v[1] << 16);
  u.y = (unsigned)v[2] | ((unsigned)v[3] << 16);
  u.z = (unsigned)v[4] | ((unsigned)v[5] << 16);
  u.w = (unsigned)v[6] | ((unsigned)v[7] << 16);
  *(uint4*)(lds + sc * 32 + 8 * ((w8 >> 3) ^ ((sc >> 1) & 3))) = u;
}

// B-fragment: lane (g,lr) reads B^T[c = nf*16+lr][k = g*8 .. g*8+7]
__device__ __forceinline__ bf16x8 bfrag(const unsigned short* lds, int g, int lr, int nf){
  int c = nf * 16 + lr;
  return ldfrag(lds + c * 32 + 8 * (g ^ ((c >> 1) & 3)));
}

// ---- init: twiddles + mlp weights + transposed bf16 bmlp weight tables ----
__global__ __launch_bounds__(256) void k_init(const float* __restrict__ mw1,
    const float* __restrict__ mw2, const float* __restrict__ w1,
    const float* __restrict__ w2,
    unsigned short* __restrict__ Awr, unsigned short* __restrict__ Awi,
    unsigned short* __restrict__ Ahc, unsigned short* __restrict__ Ahs,
    unsigned short* __restrict__ Air, unsigned short* __restrict__ Aii,
    unsigned short* __restrict__ w1s, unsigned short* __restrict__ w2c,
    unsigned short* __restrict__ w1tr, unsigned short* __restrict__ w1ti,
    unsigned short* __restrict__ w2tr, unsigned short* __restrict__ w2ti){
  int i = blockIdx.x * 256 + threadIdx.x;            // < 262144
  if (i < 49152) {                                   // Aw: 192 x 256 (kw padded)
    int m = i >> 8, w = i & 255;
    float t = (float)((m * w) & 255) / 128.0f;
    Awr[i] = f2b(cospif(t) * 0.0625f);
    Awi[i] = f2b(-sinpif(t) * 0.0625f);
  }
  if (i < 65536) {                                   // Ah: 256 x 256
    int k = i >> 8, h = i & 255;
    float t = (float)((k * h) & 255) / 128.0f;
    Ahc[i] = f2b(cospif(t) * 0.0625f);
    Ahs[i] = f2b(sinpif(t) * 0.0625f);
  }
  if (i < 32768) {                                   // Awinv: 256(w) x 128(kw), c_k folded
    int w = i >> 7, kw = i & 127;
    float t = (float)((kw * w) & 255) / 128.0f;
    float c = (kw == 0) ? 0.0625f : 0.125f;
    Air[i] = f2b(cospif(t) * c);
    Aii[i] = f2b(-sinpif(t) * c);
  }
  if (i < 8192) {                                    // bmlp W^T: [n][o][i] = w[n][i][o]
    int n = i >> 10, o = (i >> 5) & 31, ii = i & 31;
    int src = (n * BSZ + ii) * BSZ + o;
    w1tr[i] = f2b(w1[src]);
    w1ti[i] = f2b(w1[NBK * BSZ * BSZ + src]);
    w2tr[i] = f2b(w2[src]);
    w2ti[i] = f2b(w2[NBK * BSZ * BSZ + src]);
  }
  {
    int l = i >> 8, k2 = i & 255;
    w1s[(l << 8) | (k2 ^ ((l & 7) << 3))] = f2b(mw1[k2 * LAT + l]);
    int n = i >> 10, l2 = i & 1023;
    int ch = l2 >> 6, kk = l2 & 63;
    w2c[(size_t)((ch << 8) + n) * 64 + (kk ^ ((n & 7) << 3))] = f2b(mw2[l2 * CC + n]);
  }
}

// ---- LN1: bf16 out only ----
__global__ __launch_bounds__(256) void k_ln1(const float* __restrict__ in,
    const float* __restrict__ g, const float* __restrict__ b,
    unsigned short* __restrict__ outb){
  int lane = threadIdx.x & 63;
  size_t row = (size_t)blockIdx.x * 4 + (threadIdx.x >> 6);
  float4 v = ((const float4*)(in + row * CC))[lane];
  float s = wred(v.x + v.y + v.z + v.w);
  float q = wred(v.x*v.x + v.y*v.y + v.z*v.z + v.w*v.w);
  float mean = s * (1.0f/CC);
  float rstd = rsqrtf(q * (1.0f/CC) - mean*mean + 1e-5f);
  float4 gv = ((const float4*)g)[lane];
  float4 bv = ((const float4*)b)[lane];
  ushort4 ob;
  ob.x = f2b((v.x - mean) * rstd * gv.x + bv.x);
  ob.y = f2b((v.y - mean) * rstd * gv.y + bv.y);
  ob.z = f2b((v.z - mean) * rstd * gv.z + bv.z);
  ob.w = f2b((v.w - mean) * rstd * gv.w + bv.w);
  ((ushort4*)(outb + row * CC))[lane] = ob;
}

// ---- W-forward rDFT as MFMA GEMM, double-buffered staging ----
__global__ __launch_bounds__(256) void k_gw(const unsigned short* __restrict__ h1b,
    const unsigned short* __restrict__ Awr, const unsigned short* __restrict__ Awi,
    unsigned short* __restrict__ Xr, unsigned short* __restrict__ Xi){
  __shared__ __align__(16) unsigned short sb[2][2048];
  int tid = threadIdx.x, wv = tid >> 6, lane = tid & 63, g = lane >> 4, lr = lane & 15;
  int sc = tid & 63, w8 = (tid >> 6) * 8;
  int bh = blockIdx.x, m0 = blockIdx.y * 64, n0 = blockIdx.z * 64;
  const unsigned short* Bsrc = h1b + (size_t)bh * 65536 + n0;
  int arow = m0 + wv * 16 + lr;
  f32x4 aR[4], aI[4];
#pragma unroll
  for (int i = 0; i < 4; ++i) { aR[i] = (f32x4){0,0,0,0}; aI[i] = (f32x4){0,0,0,0}; }
  unsigned short vb[8];
  stage_ld(Bsrc, vb, sc, w8);
  stage_wr(vb, sb[0], sc, w8);
  __syncthreads();
  for (int ks = 0; ks < 8; ++ks) {
    int cur = ks & 1;
    if (ks < 7) stage_ld(Bsrc + (size_t)(ks + 1) * 32 * CC, vb, sc, w8);
    bf16x8 ar = ldfrag(Awr + (size_t)arow * 256 + ks * 32 + g * 8);
    bf16x8 ai = ldfrag(Awi + (size_t)arow * 256 + ks * 32 + g * 8);
#pragma unroll
    for (int nf = 0; nf < 4; ++nf) {
      bf16x8 bf = bfrag(sb[cur], g, lr, nf);
      aR[nf] = __builtin_amdgcn_mfma_f32_16x16x32_bf16(ar, bf, aR[nf], 0, 0, 0);
      aI[nf] = __builtin_amdgcn_mfma_f32_16x16x32_bf16(ai, bf, aI[nf], 0, 0, 0);
    }
    if (ks < 7) {
      stage_wr(vb, sb[cur ^ 1], sc, w8);
      __syncthreads();
    }
  }
  int b = bh >> 8, h = bh & 255;
#pragma unroll
  for (int nf = 0; nf < 4; ++nf) {
    int c = n0 + nf * 16 + lr;
#pragma unroll
    for (int r = 0; r < 4; ++r) {
      int kw = m0 + wv * 16 + g * 4 + r;
      if (kw < KF) {
        size_t o = ((size_t)(b * KF + kw) * 256 + h) * 256 + c;
        Xr[o] = f2b(aR[nf][r]);
        Xi[o] = f2b(aI[nf][r]);
      }
    }
  }
}

// ---- H-direction complex DFT, M-merged x2, double-buffered staging ----
template<int INV>
__global__ __launch_bounds__(256) void k_gh(const unsigned short* __restrict__ Bre,
    const unsigned short* __restrict__ Bim, const unsigned short* __restrict__ Ac,
    const unsigned short* __restrict__ As, unsigned short* __restrict__ Ore,
    unsigned short* __restrict__ Oim){
  __shared__ __align__(16) unsigned short sr[2][2048], si[2][2048];
  int tid = threadIdx.x, wv = tid >> 6, lane = tid & 63, g = lane >> 4, lr = lane & 15;
  int sc = tid & 63, w8 = (tid >> 6) * 8;
  int bkw = blockIdx.x, m0 = blockIdx.y * 128, n0 = blockIdx.z * 64;
  const unsigned short* srcR = Bre + (size_t)bkw * 65536 + n0;
  const unsigned short* srcI = Bim + (size_t)bkw * 65536 + n0;
  f32x4 accR[2][4], accI[2][4];
#pragma unroll
  for (int m = 0; m < 2; ++m)
#pragma unroll
    for (int i = 0; i < 4; ++i) { accR[m][i] = (f32x4){0,0,0,0}; accI[m][i] = (f32x4){0,0,0,0}; }
  unsigned short vr[8], vi[8];
  stage_ld(srcR, vr, sc, w8);
  stage_ld(srcI, vi, sc, w8);
  stage_wr(vr, sr[0], sc, w8);
  stage_wr(vi, si[0], sc, w8);
  __syncthreads();
  for (int ks = 0; ks < 8; ++ks) {
    int cur = ks & 1;
    if (ks < 7) {
      stage_ld(srcR + (size_t)(ks + 1) * 32 * CC, vr, sc, w8);
      stage_ld(srcI + (size_t)(ks + 1) * 32 * CC, vi, sc, w8);
    }
    bf16x8 bR[4], bI[4];
#pragma unroll
    for (int nf = 0; nf < 4; ++nf) { bR[nf] = bfrag(sr[cur], g, lr, nf); bI[nf] = bfrag(si[cur], g, lr, nf); }
#pragma unroll
    for (int mt = 0; mt < 2; ++mt) {
      int arow = m0 + mt * 64 + wv * 16 + lr;
      bf16x8 ac = ldfrag(Ac + (size_t)arow * 256 + ks * 32 + g * 8);
      bf16x8 as = ldfrag(As + (size_t)arow * 256 + ks * 32 + g * 8);
      bf16x8 asn = negf(as);
#pragma unroll
      for (int nf = 0; nf < 4; ++nf) {
        accR[mt][nf] = __builtin_amdgcn_mfma_f32_16x16x32_bf16(ac, bR[nf], accR[mt][nf], 0, 0, 0);
        accR[mt][nf] = __builtin_amdgcn_mfma_f32_16x16x32_bf16(INV ? asn : as, bI[nf], accR[mt][nf], 0, 0, 0);
        accI[mt][nf] = __builtin_amdgcn_mfma_f32_16x16x32_bf16(ac, bI[nf], accI[mt][nf], 0, 0, 0);
        accI[mt][nf] = __builtin_amdgcn_mfma_f32_16x16x32_bf16(INV ? as : asn, bR[nf], accI[mt][nf], 0, 0, 0);
      }
    }
    if (ks < 7) {
      stage_wr(vr, sr[cur ^ 1], sc, w8);
      stage_wr(vi, si[cur ^ 1], sc, w8);
      __syncthreads();
    }
  }
  if (!INV) {
#pragma unroll
    for (int mt = 0; mt < 2; ++mt)
#pragma unroll
      for (int nf = 0; nf < 4; ++nf) {
        int c = n0 + nf * 16 + lr;
#pragma unroll
        for (int r = 0; r < 4; ++r) {
          int kh = m0 + mt * 64 + wv * 16 + g * 4 + r;
          size_t o = ((size_t)bkw * 256 + kh) * 256 + c;
          Ore[o] = f2b(accR[mt][nf][r]);
          Oim[o] = f2b(accI[mt][nf][r]);
        }
      }
  } else {
    int b = (bkw >= KF) ? 1 : 0;
    int kw = bkw - b * KF;
#pragma unroll
    for (int mt = 0; mt < 2; ++mt)
#pragma unroll
      for (int nf = 0; nf < 4; ++nf) {
        int c = n0 + nf * 16 + lr;
#pragma unroll
        for (int r = 0; r < 4; ++r) {
          int h = m0 + mt * 64 + wv * 16 + g * 4 + r;
          size_t o = (((size_t)b * 256 + h) * KF + kw) * 256 + c;
          Ore[o] = f2b(accR[mt][nf][r]);
          Oim[o] = f2b(accI[mt][nf][r]);
        }
      }
  }
}

// ---- W-inverse rDFT + Nyquist + residuals, M-merged x2; out1 stored bf16 ----
__global__ __launch_bounds__(256) void k_gwi(const unsigned short* __restrict__ Zr,
    const unsigned short* __restrict__ Zi, const unsigned short* __restrict__ Ar,
    const unsigned short* __restrict__ Ai, const float* __restrict__ x,
    const unsigned short* __restrict__ h1b, unsigned short* __restrict__ out1b){
  __shared__ __align__(16) unsigned short sr[2][2048], si[2][2048];
  int tid = threadIdx.x, wv = tid >> 6, lane = tid & 63, g = lane >> 4, lr = lane & 15;
  int sc = tid & 63, w8 = (tid >> 6) * 8;
  int bh = blockIdx.x, m0 = blockIdx.y * 128, n0 = blockIdx.z * 64;
  const unsigned short* srcR = Zr + (size_t)bh * 33024 + n0;
  const unsigned short* srcI = Zi + (size_t)bh * 33024 + n0;
  f32x4 acc[2][4];
#pragma unroll
  for (int m = 0; m < 2; ++m)
#pragma unroll
    for (int i = 0; i < 4; ++i) acc[m][i] = (f32x4){0,0,0,0};
  unsigned short vr[8], vi[8];
  stage_ld(srcR, vr, sc, w8);
  stage_ld(srcI, vi, sc, w8);
  stage_wr(vr, sr[0], sc, w8);
  stage_wr(vi, si[0], sc, w8);
  __syncthreads();
  for (int ks = 0; ks < 4; ++ks) {
    int cur = ks & 1;
    if (ks < 3) {
      stage_ld(srcR + (size_t)(ks + 1) * 32 * CC, vr, sc, w8);
      stage_ld(srcI + (size_t)(ks + 1) * 32 * CC, vi, sc, w8);
    }
    bf16x8 bR[4], bI[4];
#pragma unroll
    for (int nf = 0; nf < 4; ++nf) { bR[nf] = bfrag(sr[cur], g, lr, nf); bI[nf] = bfrag(si[cur], g, lr, nf); }
#pragma unroll
    for (int mt = 0; mt < 2; ++mt) {
      int arow = m0 + mt * 64 + wv * 16 + lr;
      bf16x8 ar = ldfrag(Ar + (size_t)arow * 128 + ks * 32 + g * 8);
      bf16x8 ai = ldfrag(Ai + (size_t)arow * 128 + ks * 32 + g * 8);
#pragma unroll
      for (int nf = 0; nf < 4; ++nf) {
        acc[mt][nf] = __builtin_amdgcn_mfma_f32_16x16x32_bf16(ar, bR[nf], acc[mt][nf], 0, 0, 0);
        acc[mt][nf] = __builtin_amdgcn_mfma_f32_16x16x32_bf16(ai, bI[nf], acc[mt][nf], 0, 0, 0);
      }
    }
    if (ks < 3) {
      stage_wr(vr, sr[cur ^ 1], sc, w8);
      stage_wr(vi, si[cur ^ 1], sc, w8);
      __syncthreads();
    }
  }
#pragma unroll
  for (int nf = 0; nf < 4; ++nf) {
    int c = n0 + nf * 16 + lr;
    float zn = b2f(Zr[(size_t)bh * 33024 + 32768 + c]) * 0.0625f;  // kw=128, sin=0
#pragma unroll
    for (int mt = 0; mt < 2; ++mt)
#pragma unroll
      for (int r = 0; r < 4; ++r) {
        int w = m0 + mt * 64 + wv * 16 + g * 4 + r;
        size_t idx = ((size_t)bh * 256 + w) * 256 + c;
        float ny = (w & 1) ? -zn : zn;
        out1b[idx] = f2b(acc[mt][nf][r] + ny + b2f(h1b[idx]) + x[idx]);
      }
  }
}

// ---- block-diagonal complex MLP via MFMA: 64 positions/block, per-wave mids ----
__global__ __launch_bounds__(256) void k_bmlp(const unsigned short* __restrict__ Yr,
    const unsigned short* __restrict__ Yi,
    const unsigned short* __restrict__ w1tr, const unsigned short* __restrict__ w1ti,
    const unsigned short* __restrict__ w2tr, const unsigned short* __restrict__ w2ti,
    const float* __restrict__ b1, const float* __restrict__ b2,
    unsigned short* __restrict__ Or, unsigned short* __restrict__ Oi){
  __shared__ __align__(16) unsigned short mids[4][16][64];
  int tid = threadIdx.x;
  int wave = tid >> 6, lane = tid & 63;
  int g = lane >> 4, lr = lane & 15;
  size_t pos0 = (size_t)blockIdx.x * 64 + wave * 16;
  for (int n = 0; n < NBK; ++n) {
    bf16x8 axr = ldfrag(Yr + (pos0 + lr) * CC + n * BSZ + g * 8);
    bf16x8 axi = ldfrag(Yi + (pos0 + lr) * CC + n * BSZ + g * 8);
    f32x4 o1r[2], o1i[2];
#pragma unroll
    for (int nf = 0; nf < 2; ++nf) {
      bf16x8 bwr = ldfrag(w1tr + (n * BSZ + nf * 16 + lr) * BSZ + g * 8);
      bf16x8 bwi = ldfrag(w1ti + (n * BSZ + nf * 16 + lr) * BSZ + g * 8);
      f32x4 zr = (f32x4){0,0,0,0}, zi = (f32x4){0,0,0,0};
      zr = __builtin_amdgcn_mfma_f32_16x16x32_bf16(axr, bwr, zr, 0, 0, 0);
      zr = __builtin_amdgcn_mfma_f32_16x16x32_bf16(axi, negf(bwi), zr, 0, 0, 0);
      zi = __builtin_amdgcn_mfma_f32_16x16x32_bf16(axi, bwr, zi, 0, 0, 0);
      zi = __builtin_amdgcn_mfma_f32_16x16x32_bf16(axr, bwi, zi, 0, 0, 0);
      o1r[nf] = zr; o1i[nf] = zi;
    }
#pragma unroll
    for (int nf = 0; nf < 2; ++nf) {
      float br = b1[n * BSZ + nf * 16 + lr];
      float bi = b1[NBK * BSZ + n * BSZ + nf * 16 + lr];
#pragma unroll
      for (int r = 0; r < 4; ++r) {
        int row = g * 4 + r;
        int er = nf * 16 + lr;
        mids[wave][row][er ^ ((row & 7) << 3)] = f2b(fmaxf(o1r[nf][r] + br, 0.f));
        mids[wave][row][(32 + er) ^ ((row & 7) << 3)] = f2b(fmaxf(o1i[nf][r] + bi, 0.f));
      }
    }
    bf16x8 par = ldfrag(&mids[wave][lr][(g * 8) ^ ((lr & 7) << 3)]);
    bf16x8 pai = ldfrag(&mids[wave][lr][(32 + g * 8) ^ ((lr & 7) << 3)]);
#pragma unroll
    for (int nf = 0; nf < 2; ++nf) {
      bf16x8 bwr = ldfrag(w2tr + (n * BSZ + nf * 16 + lr) * BSZ + g * 8);
      bf16x8 bwi = ldfrag(w2ti + (n * BSZ + nf * 16 + lr) * BSZ + g * 8);
      f32x4 zr = (f32x4){0,0,0,0}, zi = (f32x4){0,0,0,0};
      zr = __builtin_amdgcn_mfma_f32_16x16x32_bf16(par, bwr, zr, 0, 0, 0);
      zr = __builtin_amdgcn_mfma_f32_16x16x32_bf16(pai, negf(bwi), zr, 0, 0, 0);
      zi = __builtin_amdgcn_mfma_f32_16x16x32_bf16(pai, bwr, zi, 0, 0, 0);
      zi = __builtin_amdgcn_mfma_f32_16x16x32_bf16(par, bwi, zi, 0, 0, 0);
      float cr = b2[n * BSZ + nf * 16 + lr];
      float ci = b2[NBK * BSZ + n * BSZ + nf * 16 + lr];
#pragma unroll
      for (int r = 0; r < 4; ++r) {
        float vr = zr[r] + cr, vi = zi[r] + ci;
        size_t idx = (pos0 + g * 4 + r) * CC + n * BSZ + nf * 16 + lr;
        Or[idx] = f2b((fabsf(vr) > 0.01f) ? (vr - copysignf(0.01f, vr)) : 0.f);
        Oi[idx] = f2b((fabsf(vi) > 0.01f) ? (vi - copysignf(0.01f, vi)) : 0.f);
      }
    }
  }
}

// ---- fused LN2 + MLP: round-10 structure; A-rows LayerNorm'd in-register ----
__global__ __launch_bounds__(256, 2) void k_mlp(const unsigned short* __restrict__ o1b,
    const float* __restrict__ n2g, const float* __restrict__ n2b,
    const unsigned short* __restrict__ w1s, const float* __restrict__ mb1,
    const unsigned short* __restrict__ w2c, const float* __restrict__ mb2,
    float* __restrict__ out){
  __shared__ __align__(16) unsigned short sw1[64 * 256];   // [l_local][k ^ ((l&7)<<3)]
  __shared__ __align__(16) unsigned short sw2[256 * 64];   // [n][kk ^ ((n&7)<<3)]
  __shared__ __align__(16) unsigned short mids[64][64];    // [row][e ^ ((row&7)<<3)]
  int tid = threadIdx.x;
  int wave = tid >> 6, lane = tid & 63;
  int g = lane >> 4, lr = lane & 15;
  size_t row0 = (size_t)blockIdx.x * 64;
  // ---- load A rows + inline LayerNorm (row = wave*16+lr; thread holds 64 elems) ----
  bf16x8 areg[8];
  float s = 0.f, q = 0.f;
#pragma unroll
  for (int ks = 0; ks < 8; ++ks) {
    areg[ks] = ldfrag(o1b + (row0 + wave * 16 + lr) * CC + ks * 32 + g * 8);
    u32x4 u = __builtin_bit_cast(u32x4, areg[ks]);
#pragma unroll
    for (int j = 0; j < 4; ++j) {
      float lo = __builtin_bit_cast(float, u[j] << 16);
      float hi = __builtin_bit_cast(float, u[j] & 0xffff0000u);
      s += lo + hi;
      q += lo * lo + hi * hi;
    }
  }
  // reduce across the 4 lanes sharing lr (lane = g*16+lr): xor g-bits 16 and 32
  s += __shfl_xor(s, 16, 64); s += __shfl_xor(s, 32, 64);
  q += __shfl_xor(q, 16, 64); q += __shfl_xor(q, 32, 64);
  float mean = s * (1.0f / CC);
  float rstd = rsqrtf(q * (1.0f / CC) - mean * mean + 1e-5f);
#pragma unroll
  for (int ks = 0; ks < 8; ++ks) {
    u32x4 u = __builtin_bit_cast(u32x4, areg[ks]);
    u32x4 o;
#pragma unroll
    for (int j = 0; j < 4; ++j) {
      int c0 = ks * 32 + g * 8 + j * 2;
      float lo = __builtin_bit_cast(float, u[j] << 16);
      float hi = __builtin_bit_cast(float, u[j] & 0xffff0000u);
      float nlo = (lo - mean) * rstd * n2g[c0] + n2b[c0];
      float nhi = (hi - mean) * rstd * n2g[c0 + 1] + n2b[c0 + 1];
      o[j] = (unsigned)f2b(nlo) | ((unsigned)f2b(nhi) << 16);
    }
    areg[ks] = __builtin_bit_cast(bf16x8, o);
  }
  f32x4 acc2[4][4];
#pragma unroll
  for (int mi = 0; mi < 4; ++mi)
#pragma unroll
    for (int ni = 0; ni < 4; ++ni) acc2[mi][ni] = (f32x4){0.f, 0.f, 0.f, 0.f};
  for (int ch = 0; ch < 16; ++ch) {
    __syncthreads();
    {
      const uint4* s1 = (const uint4*)(w1s + (size_t)ch * 64 * 256);
      const uint4* s2 = (const uint4*)(w2c + (size_t)ch * 256 * 64);
      uint4* d1 = (uint4*)sw1;
      uint4* d2 = (uint4*)sw2;
#pragma unroll
      for (int it = 0; it < 8; ++it) d1[it * 256 + tid] = s1[it * 256 + tid];
#pragma unroll
      for (int it = 0; it < 8; ++it) d2[it * 256 + tid] = s2[it * 256 + tid];
    }
    __syncthreads();
    f32x4 acc1[4];
#pragma unroll
    for (int s2_ = 0; s2_ < 4; ++s2_) acc1[s2_] = (f32x4){0.f, 0.f, 0.f, 0.f};
#pragma unroll
    for (int ks = 0; ks < 8; ++ks) {
#pragma unroll
      for (int s2_ = 0; s2_ < 4; ++s2_) {
        int l = s2_ * 16 + lr;
        bf16x8 bf = ldfrag(sw1 + l * 256 + ((ks * 32 + g * 8) ^ ((lr & 7) << 3)));
        acc1[s2_] = __builtin_amdgcn_mfma_f32_16x16x32_bf16(areg[ks], bf, acc1[s2_], 0, 0, 0);
      }
    }
    int l0 = ch * 64;
#pragma unroll
    for (int s2_ = 0; s2_ < 4; ++s2_) {
      float bias = mb1[l0 + s2_ * 16 + lr];
#pragma unroll
      for (int r = 0; r < 4; ++r) {
        int row = wave * 16 + g * 4 + r;
        mids[row][(s2_ * 16 + lr) ^ ((row & 7) << 3)] = f2b(gelu_t(acc1[s2_][r] + bias));
      }
    }
    __syncthreads();
#pragma unroll
    for (int ks = 0; ks < 2; ++ks) {
      bf16x8 af[4], bfv[4];
#pragma unroll
      for (int mi = 0; mi < 4; ++mi)
        af[mi] = ldfrag(&mids[mi * 16 + lr][(ks * 32 + g * 8) ^ ((lr & 7) << 3)]);
#pragma unroll
      for (int ni = 0; ni < 4; ++ni)
        bfv[ni] = ldfrag(sw2 + (wave * 64 + ni * 16 + lr) * 64 + ((ks * 32 + g * 8) ^ ((lr & 7) << 3)));
#pragma unroll
      for (int mi = 0; mi < 4; ++mi)
#pragma unroll
        for (int ni = 0; ni < 4; ++ni)
          acc2[mi][ni] = __builtin_amdgcn_mfma_f32_16x16x32_bf16(af[mi], bfv[ni], acc2[mi][ni], 0, 0, 0);
    }
  }
#pragma unroll
  for (int mi = 0; mi < 4; ++mi)
#pragma unroll
    for (int ni = 0; ni < 4; ++ni) {
      int n = wave * 64 + ni * 16 + lr;
      float bias = mb2[n];
#pragma unroll
      for (int r = 0; r < 4; ++r) {
        size_t idx = (row0 + mi * 16 + g * 4 + r) * CC + n;
        out[idx] = acc2[mi][ni][r] + bias + b2f(o1b[idx]);
      }
    }
}

extern "C" void kernel_launch(void* const* d_in, const int* in_sizes, int n_in,
                              void* d_out, int out_size, void* d_ws, size_t ws_size,
                              hipStream_t stream) {
  const float* x   = (const float*)d_in[0];
  const float* n1g = (const float*)d_in[1];
  const float* n1b = (const float*)d_in[2];
  const float* n2g = (const float*)d_in[3];
  const float* n2b = (const float*)d_in[4];
  const float* w1  = (const float*)d_in[5];
  const float* b1  = (const float*)d_in[6];
  const float* w2  = (const float*)d_in[7];
  const float* b2  = (const float*)d_in[8];
  const float* mw1 = (const float*)d_in[9];
  const float* mb1 = (const float*)d_in[10];
  const float* mw2 = (const float*)d_in[11];
  const float* mb2 = (const float*)d_in[12];
  float* out = (float*)d_out;

  char* ws = (char*)d_ws;
  unsigned short* o1b = (unsigned short*)(ws);                // out1 bf16, 67,108,864 B
  unsigned short* h1b = (unsigned short*)(ws + 134217728ull); // 67,108,864 B
  unsigned short* Xr  = (unsigned short*)(ws + 201326592ull); // 33,816,576 B (also O_r)
  unsigned short* Xi  = (unsigned short*)(ws + 235143168ull); // 33,816,576 B (also O_i)
  unsigned short* Yr  = (unsigned short*)(ws + 268959744ull); // 33,816,576 B (also Z_r)
  unsigned short* Yi  = (unsigned short*)(ws + 302776320ull); // 33,816,576 B (also Z_i)
  unsigned short* Awr = (unsigned short*)(ws + 336592896ull); // 98,304 B
  unsigned short* Awi = (unsigned short*)(ws + 336691200ull); // 98,304 B
  unsigned short* Ahc = (unsigned short*)(ws + 336789504ull); // 131,072 B
  unsigned short* Ahs = (unsigned short*)(ws + 336920576ull); // 131,072 B
  unsigned short* Air = (unsigned short*)(ws + 337051648ull); // 65,536 B
  unsigned short* Aii = (unsigned short*)(ws + 337117184ull); // 65,536 B
  unsigned short* w1s = (unsigned short*)(ws + 337182720ull); // 524,288 B
  unsigned short* w2c = (unsigned short*)(ws + 337707008ull); // 524,288 B
  unsigned short* w1tr = (unsigned short*)(ws + 338231296ull); // 16,384 B
  unsigned short* w1ti = (unsigned short*)(ws + 338247680ull); // 16,384 B
  unsigned short* w2tr = (unsigned short*)(ws + 338264064ull); // 16,384 B
  unsigned short* w2ti = (unsigned short*)(ws + 338280448ull); // 16,384 B

  k_init<<<1024, 256, 0, stream>>>(mw1, mw2, w1, w2, Awr, Awi, Ahc, Ahs, Air, Aii,
                                   w1s, w2c, w1tr, w1ti, w2tr, w2ti);
  k_ln1<<<32768, 256, 0, stream>>>(x, n1g, n1b, h1b);
  k_gw<<<dim3(512, 3, 4), 256, 0, stream>>>(h1b, Awr, Awi, Xr, Xi);
  k_gh<0><<<dim3(258, 2, 4), 256, 0, stream>>>(Xr, Xi, Ahc, Ahs, Yr, Yi);
  k_bmlp<<<1032, 256, 0, stream>>>(Yr, Yi, w1tr, w1ti, w2tr, w2ti, b1, b2, Xr, Xi);
  k_gh<1><<<dim3(258, 2, 4), 256, 0, stream>>>(Xr, Xi, Ahc, Ahs, Yr, Yi);
  k_gwi<<<dim3(512, 2, 4), 256, 0, stream>>>(Yr, Yi, Air, Aii, x, h1b, o1b);
  k_mlp<<<2048, 256, 0, stream>>>(o1b, n2g, n2b, w1s, mb1, w2c, mb2, out);
}

// Round 18
// 619.384 us; speedup vs baseline: 1.6118x; 1.0177x over previous
//
#include <hip/hip_runtime.h>
#include <math.h>

#define CC 256
#define KF 129
#define NBK 8
#define BSZ 32
#define LAT 1024

typedef __attribute__((ext_vector_type(8))) __bf16 bf16x8;
typedef __attribute__((ext_vector_type(4))) float f32x4;
typedef __attribute__((ext_vector_type(4))) unsigned u32x4;

__device__ __forceinline__ float wred(float v){
#pragma unroll
  for (int o = 32; o; o >>= 1) v += __shfl_xor(v, o, 64);
  return v;
}

// f32 -> bf16 bits, round-to-nearest-even
__device__ __forceinline__ unsigned short f2b(float f){
  unsigned u = __builtin_bit_cast(unsigned, f);
  unsigned r = u + 0x7fffu + ((u >> 16) & 1u);
  return (unsigned short)(r >> 16);
}
__device__ __forceinline__ float b2f(unsigned short h){
  unsigned u = ((unsigned)h) << 16;
  return __builtin_bit_cast(float, u);
}

__device__ __forceinline__ bf16x8 ldfrag(const unsigned short* p){
  return __builtin_bit_cast(bf16x8, *(const uint4*)p);
}
__device__ __forceinline__ bf16x8 negf(bf16x8 v){
  u32x4 u = __builtin_bit_cast(u32x4, v);
  u = u ^ 0x80008000u;
  return __builtin_bit_cast(bf16x8, u);
}

// tanh-form GELU
__device__ __forceinline__ float gelu_t(float v){
  float s = v * v;
  float t = v * fmaf(s, -0.0713575f, -1.5957691f);   // -z
  float e = __expf(t);                                // e^{-z}
  return v * __builtin_amdgcn_rcpf(1.0f + e);
}

// ---- staging split for double-buffer: load 8 u16 (one c, 8 k's) / pack+write ----
__device__ __forceinline__ void stage_ld(const unsigned short* __restrict__ gp,
    unsigned short* v, int sc, int w8){
#pragma unroll
  for (int j = 0; j < 8; ++j) v[j] = gp[(size_t)(w8 + j) * CC + sc];
}
__device__ __forceinline__ void stage_wr(const unsigned short* v,
    unsigned short* lds, int sc, int w8){
  uint4 u;
  u.x = (unsigned)v[0] | ((unsigned)v[1] << 16);
  u.y = (unsigned)v[2] | ((unsigned)v[3] << 16);
  u.z = (unsigned)v[4] | ((unsigned)v[5] << 16);
  u.w = (unsigned)v[6] | ((unsigned)v[7] << 16);
  *(uint4*)(lds + sc * 32 + 8 * ((w8 >> 3) ^ ((sc >> 1) & 3))) = u;
}

// B-fragment: lane (g,lr) reads B^T[c = nf*16+lr][k = g*8 .. g*8+7]
__device__ __forceinline__ bf16x8 bfrag(const unsigned short* lds, int g, int lr, int nf){
  int c = nf * 16 + lr;
  return ldfrag(lds + c * 32 + 8 * (g ^ ((c >> 1) & 3)));
}

// ---- init: twiddles + mlp weights + transposed bf16 bmlp weight tables ----
__global__ __launch_bounds__(256) void k_init(const float* __restrict__ mw1,
    const float* __restrict__ mw2, const float* __restrict__ w1,
    const float* __restrict__ w2,
    unsigned short* __restrict__ Awr, unsigned short* __restrict__ Awi,
    unsigned short* __restrict__ Ahc, unsigned short* __restrict__ Ahs,
    unsigned short* __restrict__ Air, unsigned short* __restrict__ Aii,
    unsigned short* __restrict__ w1s, unsigned short* __restrict__ w2c,
    unsigned short* __restrict__ w1tr, unsigned short* __restrict__ w1ti,
    unsigned short* __restrict__ w2tr, unsigned short* __restrict__ w2ti){
  int i = blockIdx.x * 256 + threadIdx.x;            // < 262144
  if (i < 49152) {                                   // Aw: 192 x 256 (kw padded)
    int m = i >> 8, w = i & 255;
    float t = (float)((m * w) & 255) / 128.0f;
    Awr[i] = f2b(cospif(t) * 0.0625f);
    Awi[i] = f2b(-sinpif(t) * 0.0625f);
  }
  if (i < 65536) {                                   // Ah: 256 x 256
    int k = i >> 8, h = i & 255;
    float t = (float)((k * h) & 255) / 128.0f;
    Ahc[i] = f2b(cospif(t) * 0.0625f);
    Ahs[i] = f2b(sinpif(t) * 0.0625f);
  }
  if (i < 32768) {                                   // Awinv: 256(w) x 128(kw), c_k folded
    int w = i >> 7, kw = i & 127;
    float t = (float)((kw * w) & 255) / 128.0f;
    float c = (kw == 0) ? 0.0625f : 0.125f;
    Air[i] = f2b(cospif(t) * c);
    Aii[i] = f2b(-sinpif(t) * c);
  }
  if (i < 8192) {                                    // bmlp W^T: [n][o][i] = w[n][i][o]
    int n = i >> 10, o = (i >> 5) & 31, ii = i & 31;
    int src = (n * BSZ + ii) * BSZ + o;
    w1tr[i] = f2b(w1[src]);
    w1ti[i] = f2b(w1[NBK * BSZ * BSZ + src]);
    w2tr[i] = f2b(w2[src]);
    w2ti[i] = f2b(w2[NBK * BSZ * BSZ + src]);
  }
  {
    int l = i >> 8, k2 = i & 255;
    w1s[(l << 8) | (k2 ^ ((l & 7) << 3))] = f2b(mw1[k2 * LAT + l]);
    int n = i >> 10, l2 = i & 1023;
    int ch = l2 >> 6, kk = l2 & 63;
    w2c[(size_t)((ch << 8) + n) * 64 + (kk ^ ((n & 7) << 3))] = f2b(mw2[l2 * CC + n]);
  }
}

// ---- LN1: bf16 out only ----
__global__ __launch_bounds__(256) void k_ln1(const float* __restrict__ in,
    const float* __restrict__ g, const float* __restrict__ b,
    unsigned short* __restrict__ outb){
  int lane = threadIdx.x & 63;
  size_t row = (size_t)blockIdx.x * 4 + (threadIdx.x >> 6);
  float4 v = ((const float4*)(in + row * CC))[lane];
  float s = wred(v.x + v.y + v.z + v.w);
  float q = wred(v.x*v.x + v.y*v.y + v.z*v.z + v.w*v.w);
  float mean = s * (1.0f/CC);
  float rstd = rsqrtf(q * (1.0f/CC) - mean*mean + 1e-5f);
  float4 gv = ((const float4*)g)[lane];
  float4 bv = ((const float4*)b)[lane];
  ushort4 ob;
  ob.x = f2b((v.x - mean) * rstd * gv.x + bv.x);
  ob.y = f2b((v.y - mean) * rstd * gv.y + bv.y);
  ob.z = f2b((v.z - mean) * rstd * gv.z + bv.z);
  ob.w = f2b((v.w - mean) * rstd * gv.w + bv.w);
  ((ushort4*)(outb + row * CC))[lane] = ob;
}

// ---- W-forward rDFT as MFMA GEMM, double-buffered staging ----
__global__ __launch_bounds__(256) void k_gw(const unsigned short* __restrict__ h1b,
    const unsigned short* __restrict__ Awr, const unsigned short* __restrict__ Awi,
    unsigned short* __restrict__ Xr, unsigned short* __restrict__ Xi){
  __shared__ __align__(16) unsigned short sb[2][2048];
  int tid = threadIdx.x, wv = tid >> 6, lane = tid & 63, g = lane >> 4, lr = lane & 15;
  int sc = tid & 63, w8 = (tid >> 6) * 8;
  int bh = blockIdx.x, m0 = blockIdx.y * 64, n0 = blockIdx.z * 64;
  const unsigned short* Bsrc = h1b + (size_t)bh * 65536 + n0;
  int arow = m0 + wv * 16 + lr;
  f32x4 aR[4], aI[4];
#pragma unroll
  for (int i = 0; i < 4; ++i) { aR[i] = (f32x4){0,0,0,0}; aI[i] = (f32x4){0,0,0,0}; }
  unsigned short vb[8];
  stage_ld(Bsrc, vb, sc, w8);
  stage_wr(vb, sb[0], sc, w8);
  __syncthreads();
  for (int ks = 0; ks < 8; ++ks) {
    int cur = ks & 1;
    if (ks < 7) stage_ld(Bsrc + (size_t)(ks + 1) * 32 * CC, vb, sc, w8);
    bf16x8 ar = ldfrag(Awr + (size_t)arow * 256 + ks * 32 + g * 8);
    bf16x8 ai = ldfrag(Awi + (size_t)arow * 256 + ks * 32 + g * 8);
#pragma unroll
    for (int nf = 0; nf < 4; ++nf) {
      bf16x8 bf = bfrag(sb[cur], g, lr, nf);
      aR[nf] = __builtin_amdgcn_mfma_f32_16x16x32_bf16(ar, bf, aR[nf], 0, 0, 0);
      aI[nf] = __builtin_amdgcn_mfma_f32_16x16x32_bf16(ai, bf, aI[nf], 0, 0, 0);
    }
    if (ks < 7) {
      stage_wr(vb, sb[cur ^ 1], sc, w8);
      __syncthreads();
    }
  }
  int b = bh >> 8, h = bh & 255;
#pragma unroll
  for (int nf = 0; nf < 4; ++nf) {
    int c = n0 + nf * 16 + lr;
#pragma unroll
    for (int r = 0; r < 4; ++r) {
      int kw = m0 + wv * 16 + g * 4 + r;
      if (kw < KF) {
        size_t o = ((size_t)(b * KF + kw) * 256 + h) * 256 + c;
        Xr[o] = f2b(aR[nf][r]);
        Xi[o] = f2b(aI[nf][r]);
      }
    }
  }
}

// ---- FUSED: H-forward complex DFT + block-diagonal complex MLP (softshrink) ----
// Main loop identical to k_gh<0>; epilogue applies the 32-ch block MLP per-wave
// (wave-private LDS transpose tiles, verified k_bmlp MFMA block) and writes O.
__global__ __launch_bounds__(256) void k_ghb(const unsigned short* __restrict__ Bre,
    const unsigned short* __restrict__ Bim, const unsigned short* __restrict__ Ac,
    const unsigned short* __restrict__ As,
    const unsigned short* __restrict__ w1tr, const unsigned short* __restrict__ w1ti,
    const unsigned short* __restrict__ w2tr, const unsigned short* __restrict__ w2ti,
    const float* __restrict__ b1, const float* __restrict__ b2,
    unsigned short* __restrict__ Ore, unsigned short* __restrict__ Oim){
  __shared__ __align__(16) unsigned short sr[2][2048], si[2][2048];   // 16 KB
  __shared__ __align__(16) unsigned short yrt[4][16][64], yit[4][16][64]; // 16 KB
  __shared__ __align__(16) unsigned short bmid[4][16][64];            // 8 KB
  int tid = threadIdx.x, wv = tid >> 6, lane = tid & 63, g = lane >> 4, lr = lane & 15;
  int sc = tid & 63, w8 = (tid >> 6) * 8;
  int bkw = blockIdx.x, m0 = blockIdx.y * 128, n0 = blockIdx.z * 64;
  const unsigned short* srcR = Bre + (size_t)bkw * 65536 + n0;
  const unsigned short* srcI = Bim + (size_t)bkw * 65536 + n0;
  f32x4 accR[2][4], accI[2][4];
#pragma unroll
  for (int m = 0; m < 2; ++m)
#pragma unroll
    for (int i = 0; i < 4; ++i) { accR[m][i] = (f32x4){0,0,0,0}; accI[m][i] = (f32x4){0,0,0,0}; }
  unsigned short vr[8], vi[8];
  stage_ld(srcR, vr, sc, w8);
  stage_ld(srcI, vi, sc, w8);
  stage_wr(vr, sr[0], sc, w8);
  stage_wr(vi, si[0], sc, w8);
  __syncthreads();
  for (int ks = 0; ks < 8; ++ks) {
    int cur = ks & 1;
    if (ks < 7) {
      stage_ld(srcR + (size_t)(ks + 1) * 32 * CC, vr, sc, w8);
      stage_ld(srcI + (size_t)(ks + 1) * 32 * CC, vi, sc, w8);
    }
    bf16x8 bR[4], bI[4];
#pragma unroll
    for (int nf = 0; nf < 4; ++nf) { bR[nf] = bfrag(sr[cur], g, lr, nf); bI[nf] = bfrag(si[cur], g, lr, nf); }
#pragma unroll
    for (int mt = 0; mt < 2; ++mt) {
      int arow = m0 + mt * 64 + wv * 16 + lr;
      bf16x8 ac = ldfrag(Ac + (size_t)arow * 256 + ks * 32 + g * 8);
      bf16x8 as = ldfrag(As + (size_t)arow * 256 + ks * 32 + g * 8);
      bf16x8 asn = negf(as);
#pragma unroll
      for (int nf = 0; nf < 4; ++nf) {
        accR[mt][nf] = __builtin_amdgcn_mfma_f32_16x16x32_bf16(ac, bR[nf], accR[mt][nf], 0, 0, 0);
        accR[mt][nf] = __builtin_amdgcn_mfma_f32_16x16x32_bf16(as, bI[nf], accR[mt][nf], 0, 0, 0);
        accI[mt][nf] = __builtin_amdgcn_mfma_f32_16x16x32_bf16(ac, bI[nf], accI[mt][nf], 0, 0, 0);
        accI[mt][nf] = __builtin_amdgcn_mfma_f32_16x16x32_bf16(asn, bR[nf], accI[mt][nf], 0, 0, 0);
      }
    }
    if (ks < 7) {
      stage_wr(vr, sr[cur ^ 1], sc, w8);
      stage_wr(vi, si[cur ^ 1], sc, w8);
      __syncthreads();
    }
  }
  // ---- fused bmlp epilogue: per-wave private (rows wv*16..+15 per mt-half) ----
#pragma unroll
  for (int mt = 0; mt < 2; ++mt) {
    // transpose this mt-half's Y (wave's 16 pos x 64 chan) into LDS, bf16
#pragma unroll
    for (int nf = 0; nf < 4; ++nf) {
#pragma unroll
      for (int r = 0; r < 4; ++r) {
        int p = g * 4 + r;
        int e = nf * 16 + lr;
        yrt[wv][p][e ^ ((p & 7) << 3)] = f2b(accR[mt][nf][r]);
        yit[wv][p][e ^ ((p & 7) << 3)] = f2b(accI[mt][nf][r]);
      }
    }
#pragma unroll
    for (int cb = 0; cb < 2; ++cb) {
      int n = (n0 >> 5) + cb;    // global 32-chan block index
      bf16x8 axr = ldfrag(&yrt[wv][lr][(cb * 32 + g * 8) ^ ((lr & 7) << 3)]);
      bf16x8 axi = ldfrag(&yit[wv][lr][(cb * 32 + g * 8) ^ ((lr & 7) << 3)]);
      f32x4 o1r[2], o1i[2];
#pragma unroll
      for (int nf = 0; nf < 2; ++nf) {
        bf16x8 bwr = ldfrag(w1tr + (n * BSZ + nf * 16 + lr) * BSZ + g * 8);
        bf16x8 bwi = ldfrag(w1ti + (n * BSZ + nf * 16 + lr) * BSZ + g * 8);
        f32x4 zr = (f32x4){0,0,0,0}, zi = (f32x4){0,0,0,0};
        zr = __builtin_amdgcn_mfma_f32_16x16x32_bf16(axr, bwr, zr, 0, 0, 0);
        zr = __builtin_amdgcn_mfma_f32_16x16x32_bf16(axi, negf(bwi), zr, 0, 0, 0);
        zi = __builtin_amdgcn_mfma_f32_16x16x32_bf16(axi, bwr, zi, 0, 0, 0);
        zi = __builtin_amdgcn_mfma_f32_16x16x32_bf16(axr, bwi, zi, 0, 0, 0);
        o1r[nf] = zr; o1i[nf] = zi;
      }
#pragma unroll
      for (int nf = 0; nf < 2; ++nf) {
        float br = b1[n * BSZ + nf * 16 + lr];
        float bi = b1[NBK * BSZ + n * BSZ + nf * 16 + lr];
#pragma unroll
        for (int r = 0; r < 4; ++r) {
          int row = g * 4 + r;
          int er = nf * 16 + lr;
          bmid[wv][row][er ^ ((row & 7) << 3)] = f2b(fmaxf(o1r[nf][r] + br, 0.f));
          bmid[wv][row][(32 + er) ^ ((row & 7) << 3)] = f2b(fmaxf(o1i[nf][r] + bi, 0.f));
        }
      }
      bf16x8 par = ldfrag(&bmid[wv][lr][(g * 8) ^ ((lr & 7) << 3)]);
      bf16x8 pai = ldfrag(&bmid[wv][lr][(32 + g * 8) ^ ((lr & 7) << 3)]);
#pragma unroll
      for (int nf = 0; nf < 2; ++nf) {
        bf16x8 bwr = ldfrag(w2tr + (n * BSZ + nf * 16 + lr) * BSZ + g * 8);
        bf16x8 bwi = ldfrag(w2ti + (n * BSZ + nf * 16 + lr) * BSZ + g * 8);
        f32x4 zr = (f32x4){0,0,0,0}, zi = (f32x4){0,0,0,0};
        zr = __builtin_amdgcn_mfma_f32_16x16x32_bf16(par, bwr, zr, 0, 0, 0);
        zr = __builtin_amdgcn_mfma_f32_16x16x32_bf16(pai, negf(bwi), zr, 0, 0, 0);
        zi = __builtin_amdgcn_mfma_f32_16x16x32_bf16(pai, bwr, zi, 0, 0, 0);
        zi = __builtin_amdgcn_mfma_f32_16x16x32_bf16(par, bwi, zi, 0, 0, 0);
        float cr = b2[n * BSZ + nf * 16 + lr];
        float ci = b2[NBK * BSZ + n * BSZ + nf * 16 + lr];
#pragma unroll
        for (int r = 0; r < 4; ++r) {
          float vr2 = zr[r] + cr, vi2 = zi[r] + ci;
          int kh = m0 + mt * 64 + wv * 16 + g * 4 + r;
          int c = n0 + cb * 32 + nf * 16 + lr;
          size_t o = ((size_t)bkw * 256 + kh) * 256 + c;
          Ore[o] = f2b((fabsf(vr2) > 0.01f) ? (vr2 - copysignf(0.01f, vr2)) : 0.f);
          Oim[o] = f2b((fabsf(vi2) > 0.01f) ? (vi2 - copysignf(0.01f, vi2)) : 0.f);
        }
      }
    }
  }
}

// ---- H-inverse complex DFT, M-merged x2, double-buffered staging ----
__global__ __launch_bounds__(256) void k_ghi(const unsigned short* __restrict__ Bre,
    const unsigned short* __restrict__ Bim, const unsigned short* __restrict__ Ac,
    const unsigned short* __restrict__ As, unsigned short* __restrict__ Ore,
    unsigned short* __restrict__ Oim){
  __shared__ __align__(16) unsigned short sr[2][2048], si[2][2048];
  int tid = threadIdx.x, wv = tid >> 6, lane = tid & 63, g = lane >> 4, lr = lane & 15;
  int sc = tid & 63, w8 = (tid >> 6) * 8;
  int bkw = blockIdx.x, m0 = blockIdx.y * 128, n0 = blockIdx.z * 64;
  const unsigned short* srcR = Bre + (size_t)bkw * 65536 + n0;
  const unsigned short* srcI = Bim + (size_t)bkw * 65536 + n0;
  f32x4 accR[2][4], accI[2][4];
#pragma unroll
  for (int m = 0; m < 2; ++m)
#pragma unroll
    for (int i = 0; i < 4; ++i) { accR[m][i] = (f32x4){0,0,0,0}; accI[m][i] = (f32x4){0,0,0,0}; }
  unsigned short vr[8], vi[8];
  stage_ld(srcR, vr, sc, w8);
  stage_ld(srcI, vi, sc, w8);
  stage_wr(vr, sr[0], sc, w8);
  stage_wr(vi, si[0], sc, w8);
  __syncthreads();
  for (int ks = 0; ks < 8; ++ks) {
    int cur = ks & 1;
    if (ks < 7) {
      stage_ld(srcR + (size_t)(ks + 1) * 32 * CC, vr, sc, w8);
      stage_ld(srcI + (size_t)(ks + 1) * 32 * CC, vi, sc, w8);
    }
    bf16x8 bR[4], bI[4];
#pragma unroll
    for (int nf = 0; nf < 4; ++nf) { bR[nf] = bfrag(sr[cur], g, lr, nf); bI[nf] = bfrag(si[cur], g, lr, nf); }
#pragma unroll
    for (int mt = 0; mt < 2; ++mt) {
      int arow = m0 + mt * 64 + wv * 16 + lr;
      bf16x8 ac = ldfrag(Ac + (size_t)arow * 256 + ks * 32 + g * 8);
      bf16x8 as = ldfrag(As + (size_t)arow * 256 + ks * 32 + g * 8);
      bf16x8 asn = negf(as);
#pragma unroll
      for (int nf = 0; nf < 4; ++nf) {
        accR[mt][nf] = __builtin_amdgcn_mfma_f32_16x16x32_bf16(ac, bR[nf], accR[mt][nf], 0, 0, 0);
        accR[mt][nf] = __builtin_amdgcn_mfma_f32_16x16x32_bf16(asn, bI[nf], accR[mt][nf], 0, 0, 0);
        accI[mt][nf] = __builtin_amdgcn_mfma_f32_16x16x32_bf16(ac, bI[nf], accI[mt][nf], 0, 0, 0);
        accI[mt][nf] = __builtin_amdgcn_mfma_f32_16x16x32_bf16(as, bR[nf], accI[mt][nf], 0, 0, 0);
      }
    }
    if (ks < 7) {
      stage_wr(vr, sr[cur ^ 1], sc, w8);
      stage_wr(vi, si[cur ^ 1], sc, w8);
      __syncthreads();
    }
  }
  int b = (bkw >= KF) ? 1 : 0;
  int kw = bkw - b * KF;
#pragma unroll
  for (int mt = 0; mt < 2; ++mt)
#pragma unroll
    for (int nf = 0; nf < 4; ++nf) {
      int c = n0 + nf * 16 + lr;
#pragma unroll
      for (int r = 0; r < 4; ++r) {
        int h = m0 + mt * 64 + wv * 16 + g * 4 + r;
        size_t o = (((size_t)b * 256 + h) * KF + kw) * 256 + c;
        Ore[o] = f2b(accR[mt][nf][r]);
        Oim[o] = f2b(accI[mt][nf][r]);
      }
    }
}

// ---- W-inverse rDFT + Nyquist + residuals, M-merged x2; out1 stored bf16 ----
__global__ __launch_bounds__(256) void k_gwi(const unsigned short* __restrict__ Zr,
    const unsigned short* __restrict__ Zi, const unsigned short* __restrict__ Ar,
    const unsigned short* __restrict__ Ai, const float* __restrict__ x,
    const unsigned short* __restrict__ h1b, unsigned short* __restrict__ out1b){
  __shared__ __align__(16) unsigned short sr[2][2048], si[2][2048];
  int tid = threadIdx.x, wv = tid >> 6, lane = tid & 63, g = lane >> 4, lr = lane & 15;
  int sc = tid & 63, w8 = (tid >> 6) * 8;
  int bh = blockIdx.x, m0 = blockIdx.y * 128, n0 = blockIdx.z * 64;
  const unsigned short* srcR = Zr + (size_t)bh * 33024 + n0;
  const unsigned short* srcI = Zi + (size_t)bh * 33024 + n0;
  f32x4 acc[2][4];
#pragma unroll
  for (int m = 0; m < 2; ++m)
#pragma unroll
    for (int i = 0; i < 4; ++i) acc[m][i] = (f32x4){0,0,0,0};
  unsigned short vr[8], vi[8];
  stage_ld(srcR, vr, sc, w8);
  stage_ld(srcI, vi, sc, w8);
  stage_wr(vr, sr[0], sc, w8);
  stage_wr(vi, si[0], sc, w8);
  __syncthreads();
  for (int ks = 0; ks < 4; ++ks) {
    int cur = ks & 1;
    if (ks < 3) {
      stage_ld(srcR + (size_t)(ks + 1) * 32 * CC, vr, sc, w8);
      stage_ld(srcI + (size_t)(ks + 1) * 32 * CC, vi, sc, w8);
    }
    bf16x8 bR[4], bI[4];
#pragma unroll
    for (int nf = 0; nf < 4; ++nf) { bR[nf] = bfrag(sr[cur], g, lr, nf); bI[nf] = bfrag(si[cur], g, lr, nf); }
#pragma unroll
    for (int mt = 0; mt < 2; ++mt) {
      int arow = m0 + mt * 64 + wv * 16 + lr;
      bf16x8 ar = ldfrag(Ar + (size_t)arow * 128 + ks * 32 + g * 8);
      bf16x8 ai = ldfrag(Ai + (size_t)arow * 128 + ks * 32 + g * 8);
#pragma unroll
      for (int nf = 0; nf < 4; ++nf) {
        acc[mt][nf] = __builtin_amdgcn_mfma_f32_16x16x32_bf16(ar, bR[nf], acc[mt][nf], 0, 0, 0);
        acc[mt][nf] = __builtin_amdgcn_mfma_f32_16x16x32_bf16(ai, bI[nf], acc[mt][nf], 0, 0, 0);
      }
    }
    if (ks < 3) {
      stage_wr(vr, sr[cur ^ 1], sc, w8);
      stage_wr(vi, si[cur ^ 1], sc, w8);
      __syncthreads();
    }
  }
#pragma unroll
  for (int nf = 0; nf < 4; ++nf) {
    int c = n0 + nf * 16 + lr;
    float zn = b2f(Zr[(size_t)bh * 33024 + 32768 + c]) * 0.0625f;  // kw=128, sin=0
#pragma unroll
    for (int mt = 0; mt < 2; ++mt)
#pragma unroll
      for (int r = 0; r < 4; ++r) {
        int w = m0 + mt * 64 + wv * 16 + g * 4 + r;
        size_t idx = ((size_t)bh * 256 + w) * 256 + c;
        float ny = (w & 1) ? -zn : zn;
        out1b[idx] = f2b(acc[mt][nf][r] + ny + b2f(h1b[idx]) + x[idx]);
      }
  }
}

// ---- fused LN2 + MLP: round-10 structure; A-rows LayerNorm'd in-register ----
__global__ __launch_bounds__(256, 2) void k_mlp(const unsigned short* __restrict__ o1b,
    const float* __restrict__ n2g, const float* __restrict__ n2b,
    const unsigned short* __restrict__ w1s, const float* __restrict__ mb1,
    const unsigned short* __restrict__ w2c, const float* __restrict__ mb2,
    float* __restrict__ out){
  __shared__ __align__(16) unsigned short sw1[64 * 256];
  __shared__ __align__(16) unsigned short sw2[256 * 64];
  __shared__ __align__(16) unsigned short mids[64][64];
  int tid = threadIdx.x;
  int wave = tid >> 6, lane = tid & 63;
  int g = lane >> 4, lr = lane & 15;
  size_t row0 = (size_t)blockIdx.x * 64;
  bf16x8 areg[8];
  float s = 0.f, q = 0.f;
#pragma unroll
  for (int ks = 0; ks < 8; ++ks) {
    areg[ks] = ldfrag(o1b + (row0 + wave * 16 + lr) * CC + ks * 32 + g * 8);
    u32x4 u = __builtin_bit_cast(u32x4, areg[ks]);
#pragma unroll
    for (int j = 0; j < 4; ++j) {
      float lo = __builtin_bit_cast(float, u[j] << 16);
      float hi = __builtin_bit_cast(float, u[j] & 0xffff0000u);
      s += lo + hi;
      q += lo * lo + hi * hi;
    }
  }
  s += __shfl_xor(s, 16, 64); s += __shfl_xor(s, 32, 64);
  q += __shfl_xor(q, 16, 64); q += __shfl_xor(q, 32, 64);
  float mean = s * (1.0f / CC);
  float rstd = rsqrtf(q * (1.0f / CC) - mean * mean + 1e-5f);
#pragma unroll
  for (int ks = 0; ks < 8; ++ks) {
    u32x4 u = __builtin_bit_cast(u32x4, areg[ks]);
    u32x4 o;
#pragma unroll
    for (int j = 0; j < 4; ++j) {
      int c0 = ks * 32 + g * 8 + j * 2;
      float lo = __builtin_bit_cast(float, u[j] << 16);
      float hi = __builtin_bit_cast(float, u[j] & 0xffff0000u);
      float nlo = (lo - mean) * rstd * n2g[c0] + n2b[c0];
      float nhi = (hi - mean) * rstd * n2g[c0 + 1] + n2b[c0 + 1];
      o[j] = (unsigned)f2b(nlo) | ((unsigned)f2b(nhi) << 16);
    }
    areg[ks] = __builtin_bit_cast(bf16x8, o);
  }
  f32x4 acc2[4][4];
#pragma unroll
  for (int mi = 0; mi < 4; ++mi)
#pragma unroll
    for (int ni = 0; ni < 4; ++ni) acc2[mi][ni] = (f32x4){0.f, 0.f, 0.f, 0.f};
  for (int ch = 0; ch < 16; ++ch) {
    __syncthreads();
    {
      const uint4* s1 = (const uint4*)(w1s + (size_t)ch * 64 * 256);
      const uint4* s2 = (const uint4*)(w2c + (size_t)ch * 256 * 64);
      uint4* d1 = (uint4*)sw1;
      uint4* d2 = (uint4*)sw2;
#pragma unroll
      for (int it = 0; it < 8; ++it) d1[it * 256 + tid] = s1[it * 256 + tid];
#pragma unroll
      for (int it = 0; it < 8; ++it) d2[it * 256 + tid] = s2[it * 256 + tid];
    }
    __syncthreads();
    f32x4 acc1[4];
#pragma unroll
    for (int s2_ = 0; s2_ < 4; ++s2_) acc1[s2_] = (f32x4){0.f, 0.f, 0.f, 0.f};
#pragma unroll
    for (int ks = 0; ks < 8; ++ks) {
#pragma unroll
      for (int s2_ = 0; s2_ < 4; ++s2_) {
        int l = s2_ * 16 + lr;
        bf16x8 bf = ldfrag(sw1 + l * 256 + ((ks * 32 + g * 8) ^ ((lr & 7) << 3)));
        acc1[s2_] = __builtin_amdgcn_mfma_f32_16x16x32_bf16(areg[ks], bf, acc1[s2_], 0, 0, 0);
      }
    }
    int l0 = ch * 64;
#pragma unroll
    for (int s2_ = 0; s2_ < 4; ++s2_) {
      float bias = mb1[l0 + s2_ * 16 + lr];
#pragma unroll
      for (int r = 0; r < 4; ++r) {
        int row = wave * 16 + g * 4 + r;
        mids[row][(s2_ * 16 + lr) ^ ((row & 7) << 3)] = f2b(gelu_t(acc1[s2_][r] + bias));
      }
    }
    __syncthreads();
#pragma unroll
    for (int ks = 0; ks < 2; ++ks) {
      bf16x8 af[4], bfv[4];
#pragma unroll
      for (int mi = 0; mi < 4; ++mi)
        af[mi] = ldfrag(&mids[mi * 16 + lr][(ks * 32 + g * 8) ^ ((lr & 7) << 3)]);
#pragma unroll
      for (int ni = 0; ni < 4; ++ni)
        bfv[ni] = ldfrag(sw2 + (wave * 64 + ni * 16 + lr) * 64 + ((ks * 32 + g * 8) ^ ((lr & 7) << 3)));
#pragma unroll
      for (int mi = 0; mi < 4; ++mi)
#pragma unroll
        for (int ni = 0; ni < 4; ++ni)
          acc2[mi][ni] = __builtin_amdgcn_mfma_f32_16x16x32_bf16(af[mi], bfv[ni], acc2[mi][ni], 0, 0, 0);
    }
  }
#pragma unroll
  for (int mi = 0; mi < 4; ++mi)
#pragma unroll
    for (int ni = 0; ni < 4; ++ni) {
      int n = wave * 64 + ni * 16 + lr;
      float bias = mb2[n];
#pragma unroll
      for (int r = 0; r < 4; ++r) {
        size_t idx = (row0 + mi * 16 + g * 4 + r) * CC + n;
        out[idx] = acc2[mi][ni][r] + bias + b2f(o1b[idx]);
      }
    }
}

extern "C" void kernel_launch(void* const* d_in, const int* in_sizes, int n_in,
                              void* d_out, int out_size, void* d_ws, size_t ws_size,
                              hipStream_t stream) {
  const float* x   = (const float*)d_in[0];
  const float* n1g = (const float*)d_in[1];
  const float* n1b = (const float*)d_in[2];
  const float* n2g = (const float*)d_in[3];
  const float* n2b = (const float*)d_in[4];
  const float* w1  = (const float*)d_in[5];
  const float* b1  = (const float*)d_in[6];
  const float* w2  = (const float*)d_in[7];
  const float* b2  = (const float*)d_in[8];
  const float* mw1 = (const float*)d_in[9];
  const float* mb1 = (const float*)d_in[10];
  const float* mw2 = (const float*)d_in[11];
  const float* mb2 = (const float*)d_in[12];
  float* out = (float*)d_out;

  char* ws = (char*)d_ws;
  unsigned short* o1b = (unsigned short*)(ws);                // out1 bf16, 67,108,864 B
  unsigned short* h1b = (unsigned short*)(ws + 134217728ull); // 67,108,864 B
  unsigned short* Xr  = (unsigned short*)(ws + 201326592ull); // 33,816,576 B (also O_r)
  unsigned short* Xi  = (unsigned short*)(ws + 235143168ull); // 33,816,576 B (also O_i)
  unsigned short* Yr  = (unsigned short*)(ws + 268959744ull); // 33,816,576 B (Z_r)
  unsigned short* Yi  = (unsigned short*)(ws + 302776320ull); // 33,816,576 B (Z_i)
  unsigned short* Awr = (unsigned short*)(ws + 336592896ull); // 98,304 B
  unsigned short* Awi = (unsigned short*)(ws + 336691200ull); // 98,304 B
  unsigned short* Ahc = (unsigned short*)(ws + 336789504ull); // 131,072 B
  unsigned short* Ahs = (unsigned short*)(ws + 336920576ull); // 131,072 B
  unsigned short* Air = (unsigned short*)(ws + 337051648ull); // 65,536 B
  unsigned short* Aii = (unsigned short*)(ws + 337117184ull); // 65,536 B
  unsigned short* w1s = (unsigned short*)(ws + 337182720ull); // 524,288 B
  unsigned short* w2c = (unsigned short*)(ws + 337707008ull); // 524,288 B
  unsigned short* w1tr = (unsigned short*)(ws + 338231296ull); // 16,384 B
  unsigned short* w1ti = (unsigned short*)(ws + 338247680ull); // 16,384 B
  unsigned short* w2tr = (unsigned short*)(ws + 338264064ull); // 16,384 B
  unsigned short* w2ti = (unsigned short*)(ws + 338280448ull); // 16,384 B

  k_init<<<1024, 256, 0, stream>>>(mw1, mw2, w1, w2, Awr, Awi, Ahc, Ahs, Air, Aii,
                                   w1s, w2c, w1tr, w1ti, w2tr, w2ti);
  k_ln1<<<32768, 256, 0, stream>>>(x, n1g, n1b, h1b);
  k_gw<<<dim3(512, 3, 4), 256, 0, stream>>>(h1b, Awr, Awi, Xr, Xi);
  // fused H-forward DFT + block-diag MLP: X -> O (written to Yr/Yi)
  k_ghb<<<dim3(258, 2, 4), 256, 0, stream>>>(Xr, Xi, Ahc, Ahs,
                                             w1tr, w1ti, w2tr, w2ti, b1, b2, Yr, Yi);
  // H-inverse DFT: O -> Z (written to Xr/Xi)
  k_ghi<<<dim3(258, 2, 4), 256, 0, stream>>>(Yr, Yi, Ahc, Ahs, Xr, Xi);
  k_gwi<<<dim3(512, 2, 4), 256, 0, stream>>>(Xr, Xi, Air, Aii, x, h1b, o1b);
  k_mlp<<<2048, 256, 0, stream>>>(o1b, n2g, n2b, w1s, mb1, w2c, mb2, out);
}